// Round 11
// baseline (331.906 us; speedup 1.0000x reference)
//
#include <hip/hip_runtime.h>
#include <hip/hip_bf16.h>

typedef unsigned short u16;
typedef unsigned int u32;

#define MAXB 2048
#define POOL_MAXG 64

typedef __attribute__((ext_vector_type(8))) short bf16x8;
typedef __attribute__((ext_vector_type(4))) float f32x4;

__device__ __forceinline__ float bf2f(u16 u) { return __uint_as_float(((u32)u) << 16); }
__device__ __forceinline__ float bl(u32 u) { return __uint_as_float(u << 16); }
__device__ __forceinline__ float bh(u32 u) { return __uint_as_float(u & 0xffff0000u); }
__device__ __forceinline__ u16 f2bf(float f) {
    u32 u = __float_as_uint(f);
    u += 0x7fffu + ((u >> 16) & 1u);   // round-to-nearest-even
    return (u16)(u >> 16);
}
__device__ __forceinline__ float lrelu(float x) { return x > 0.f ? x : 0.2f * x; }
__device__ __forceinline__ int clampi(int v, int lo, int hi) {
    return v < lo ? lo : (v > hi ? hi : v);
}
__device__ __forceinline__ float load1(const void* base, int idx, int f32) {
    return f32 ? ((const float*)base)[idx] : bf2f(((const u16*)base)[idx]);
}
// softmax without max-shift: clamp keeps exp finite; shift-invariance => same ratios.
__device__ __forceinline__ float cexpf(float a) {
    return __builtin_amdgcn_exp2f(fminf(a, 30.f) * 1.4426950408889634f);
}

// ---------------- init: dtype detect + consts + zero bcnt/pool/done (merged) ------------
// flag[0]=dtype flag, flag[1]=bhist done-counter, flag[2]=pool done-counter
__global__ void k_init(const u32* __restrict__ xw, int* __restrict__ flag,
                       int* __restrict__ bcnt, int B,
                       const void* We1, const void* ae1, const void* We2, const void* ae2,
                       const void* as1, const void* ad1, const void* as2, const void* ad2,
                       float* __restrict__ consts, float* __restrict__ pool, int psize) {
    __shared__ int sf;
    int t = threadIdx.x;
    for (int i = t; i < B; i += 256) bcnt[i] = 0;
    if (t < 64) {
        int cnt = 0;
        #pragma unroll
        for (int j = 0; j < 4; j++) {
            u32 w = xw[t * 4 + j];
            int e0 = (int)((w >> 7) & 0xffu);
            int e1 = (int)((w >> 23) & 0xffu);
            cnt += (e0 >= 0x60 && e0 <= 0x8f);
            cnt += (e1 >= 0x60 && e1 <= 0x8f);
        }
        #pragma unroll
        for (int off = 32; off > 0; off >>= 1) cnt += __shfl_xor(cnt, off);
        if (t == 0) {
            int v = (cnt < 480) ? 1 : 0;
            flag[0] = v; flag[1] = 0; flag[2] = 0; sf = v;
        }
    }
    __syncthreads();
    int f = sf;
    for (int i = t; i < psize; i += 256) pool[i] = 0.f;
    if (t < 4) {
        float s = 0.f;
        for (int c = 0; c < 32; c++) s += load1(We1, t * 32 + c, f) * load1(ae1, t * 32 + c, f);
        consts[t] = s;
    } else if (t == 4) {
        float s = 0.f;
        for (int c = 0; c < 64; c++) s += load1(We2, c, f) * load1(ae2, c, f);
        consts[4] = s;
    }
    if (t < 128) {
        consts[8 + t] = load1(as1, t, f);
        consts[136 + t] = load1(ad1, t, f);
    }
    if (t < 64) {
        consts[264 + t] = load1(as2, t, f);
        consts[328 + t] = load1(ad2, t, f);
    }
}

// ---------------- GEMM device body: 2 tiles/block concurrent + fused coef epilogue -------
template <int NC>
__device__ __forceinline__ void dev_gemm(
    u16* __restrict__ Bf,   // LDS arena: 2*(NC/16)*4*64*8 u16
    const void* __restrict__ X, const void* __restrict__ Wg, bool fX, bool fW,
    u16* __restrict__ Y, const float* __restrict__ consts,
    float* __restrict__ casrc, float* __restrict__ cadst,
    int nrows, int bid, int nblocks) {
    constexpr int NCT = NC / 16;
    const int tid = threadIdx.x;
    const int wid = tid >> 6, lane = tid & 63;
    auto bfi = [&](int hh, int t, int s, int l, int j) {
        return ((((hh)*NCT + t) * 4 + s) * 64 + l) * 8 + j;
    };

    // ---- stage W -> LDS (coalesced global reads, scattered 2B LDS writes) ----
    if (fW) {
        const float* W4 = (const float*)Wg;
        for (int g = tid; g < 128 * NC / 4; g += 256) {
            int e = g * 4;
            int r = e / NC;
            int c = e % NC;
            int k = (NC == 64) ? ((r < 64) ? 2 * r : 2 * (r - 64) + 1) : r;
            int s = k >> 5;
            int kk = k & 31;
            int lhi = (kk >> 3) << 4;
            int j = kk & 7;
            float4 v = *(const float4*)(W4 + e);
            float vv[4] = {v.x, v.y, v.z, v.w};
            #pragma unroll
            for (int q = 0; q < 4; q++) {
                int col = c + q;
                int t = col >> 4, l = lhi | (col & 15);
                u16 h = f2bf(vv[q]);
                Bf[bfi(0, t, s, l, j)] = h;
                Bf[bfi(1, t, s, l, j)] = f2bf(vv[q] - bf2f(h));
            }
        }
    } else {
        const u16* Wb = (const u16*)Wg;
        for (int g = tid; g < 128 * NC / 8; g += 256) {
            int e = g * 8;
            int r = e / NC;
            int c = e % NC;
            int k = (NC == 64) ? ((r < 64) ? 2 * r : 2 * (r - 64) + 1) : r;
            int s = k >> 5;
            int kk = k & 31;
            int lhi = (kk >> 3) << 4;
            int j = kk & 7;
            uint4 v = *(const uint4*)(Wb + e);
            u16 arr[8] = {(u16)v.x, (u16)(v.x >> 16), (u16)v.y, (u16)(v.y >> 16),
                          (u16)v.z, (u16)(v.z >> 16), (u16)v.w, (u16)(v.w >> 16)};
            #pragma unroll
            for (int q = 0; q < 8; q++) {
                int col = c + q;
                int t = col >> 4, l = lhi | (col & 15);
                Bf[bfi(0, t, s, l, j)] = arr[q];
            }
        }
    }
    __syncthreads();

    const int tileIds[2] = {bid, bid + nblocks};

    // ---- A fragments for BOTH tiles: all loads issued together ----
    bf16x8 ahi[2][4], alo[2][4];
    #pragma unroll
    for (int tt = 0; tt < 2; tt++) {
        const int rowbase = tileIds[tt] * 64 + wid * 16;
        const int arow = rowbase + (lane & 15);
        const bool rv = arow < nrows;
        #pragma unroll
        for (int s = 0; s < 4; s++) {
            int koff = s * 32 + (lane >> 4) * 8;
            u16 h[8], l8[8];
            #pragma unroll
            for (int j = 0; j < 8; j++) { h[j] = 0; l8[j] = 0; }
            if (rv) {
                if (fX) {
                    const float* xp = (const float*)X + (size_t)arow * 128 + koff;
                    float4 a = *(const float4*)xp;
                    float4 b = *(const float4*)(xp + 4);
                    float vv[8];
                    vv[0] = a.x; vv[1] = a.y; vv[2] = a.z; vv[3] = a.w;
                    vv[4] = b.x; vv[5] = b.y; vv[6] = b.z; vv[7] = b.w;
                    #pragma unroll
                    for (int j = 0; j < 8; j++) {
                        h[j] = f2bf(vv[j]);
                        l8[j] = f2bf(vv[j] - bf2f(h[j]));
                    }
                } else {
                    const u16* xp = (const u16*)X + (size_t)arow * 128 + koff;
                    uint4 q = *(const uint4*)xp;
                    h[0] = (u16)q.x; h[1] = (u16)(q.x >> 16);
                    h[2] = (u16)q.y; h[3] = (u16)(q.y >> 16);
                    h[4] = (u16)q.z; h[5] = (u16)(q.z >> 16);
                    h[6] = (u16)q.w; h[7] = (u16)(q.w >> 16);
                }
            }
            bf16x8 vh, vl;
            #pragma unroll
            for (int j = 0; j < 8; j++) { vh[j] = (short)h[j]; vl[j] = (short)l8[j]; }
            ahi[tt][s] = vh; alo[tt][s] = vl;
        }
    }

    // ---- MFMA: each B-frag read feeds both tiles ----
    f32x4 acc[2][NCT];
    #pragma unroll
    for (int tt = 0; tt < 2; tt++)
        #pragma unroll
        for (int t = 0; t < NCT; t++) acc[tt][t] = (f32x4){0.f, 0.f, 0.f, 0.f};
    #pragma unroll
    for (int s = 0; s < 4; s++) {
        #pragma unroll
        for (int t = 0; t < NCT; t++) {
            bf16x8 bhi = *(const bf16x8*)(Bf + bfi(0, t, s, lane, 0));
            acc[0][t] = __builtin_amdgcn_mfma_f32_16x16x32_bf16(ahi[0][s], bhi, acc[0][t], 0, 0, 0);
            acc[1][t] = __builtin_amdgcn_mfma_f32_16x16x32_bf16(ahi[1][s], bhi, acc[1][t], 0, 0, 0);
            if (fW) {
                bf16x8 blo = *(const bf16x8*)(Bf + bfi(1, t, s, lane, 0));
                acc[0][t] = __builtin_amdgcn_mfma_f32_16x16x32_bf16(ahi[0][s], blo, acc[0][t], 0, 0, 0);
                acc[1][t] = __builtin_amdgcn_mfma_f32_16x16x32_bf16(ahi[1][s], blo, acc[1][t], 0, 0, 0);
            }
            if (fX) {
                acc[0][t] = __builtin_amdgcn_mfma_f32_16x16x32_bf16(alo[0][s], bhi, acc[0][t], 0, 0, 0);
                acc[1][t] = __builtin_amdgcn_mfma_f32_16x16x32_bf16(alo[1][s], bhi, acc[1][t], 0, 0, 0);
            }
        }
    }

    // ---- store + fused coef epilogue, per tile ----
    #pragma unroll
    for (int tt = 0; tt < 2; tt++) {
        const int rowbase = tileIds[tt] * 64 + wid * 16;
        const int l16 = lane & 15;
        #pragma unroll
        for (int reg = 0; reg < 4; reg++) {
            int r = rowbase + (lane >> 4) * 4 + reg;
            if (r < nrows) {
                if constexpr (NC == 128) {
                    #pragma unroll
                    for (int t = 0; t < 4; t++) {
                        u32 w = (u32)f2bf(acc[tt][t][reg])
                              | ((u32)f2bf(acc[tt][t + 4][reg]) << 16);
                        ((u32*)Y)[(size_t)r * 64 + t * 16 + l16] = w;
                    }
                } else {
                    #pragma unroll
                    for (int t = 0; t < 4; t++)
                        Y[(size_t)r * 64 + t * 16 + l16] = f2bf(acc[tt][t][reg]);
                }
            }
        }
        if (casrc) {
            if constexpr (NC == 128) {
                #pragma unroll
                for (int reg = 0; reg < 4; reg++) {
                    int r = rowbase + (lane >> 4) * 4 + reg;
                    float pA[4] = {0.f, 0.f, 0.f, 0.f};
                    float pD[4] = {0.f, 0.f, 0.f, 0.f};
                    #pragma unroll
                    for (int t = 0; t < 4; t++) {
                        int p = t * 16 + l16;
                        int g = t >> 1;
                        pA[g]     += acc[tt][t][reg]     * consts[8 + p];
                        pD[g]     += acc[tt][t][reg]     * consts[136 + p];
                        pA[g + 2] += acc[tt][t + 4][reg] * consts[72 + p];
                        pD[g + 2] += acc[tt][t + 4][reg] * consts[200 + p];
                    }
                    #pragma unroll
                    for (int off = 1; off < 16; off <<= 1) {
                        #pragma unroll
                        for (int g = 0; g < 4; g++) {
                            pA[g] += __shfl_xor(pA[g], off);
                            pD[g] += __shfl_xor(pD[g], off);
                        }
                    }
                    if (l16 == 0 && r < nrows) {
                        #pragma unroll
                        for (int g = 0; g < 4; g++) {
                            casrc[r * 4 + g] = pA[g];
                            cadst[r * 4 + g] = pD[g];
                        }
                    }
                }
            } else {
                #pragma unroll
                for (int reg = 0; reg < 4; reg++) {
                    int r = rowbase + (lane >> 4) * 4 + reg;
                    float s1 = 0.f, s2 = 0.f;
                    #pragma unroll
                    for (int t = 0; t < 4; t++) {
                        int p = t * 16 + l16;
                        s1 += acc[tt][t][reg] * consts[264 + p];
                        s2 += acc[tt][t][reg] * consts[328 + p];
                    }
                    #pragma unroll
                    for (int off = 1; off < 16; off <<= 1) {
                        s1 += __shfl_xor(s1, off);
                        s2 += __shfl_xor(s2, off);
                    }
                    if (l16 == 0 && r < nrows) { casrc[r] = s1; cadst[r] = s2; }
                }
            }
        }
    }
}

// ---------------- binA device body: tile-ranked bucket scatter -> stagedA ---------------
__device__ __forceinline__ void dev_binA(
    int* __restrict__ smem,   // LDS arena: lhist[MAXB], lbase[MAXB]
    const int* __restrict__ dst, const int* __restrict__ src, const void* eattr,
    int f, int* __restrict__ bfront, int2* __restrict__ stagedA,
    int E, int n, int B, int bid, int nblk) {
    int* lhist = smem;
    int* lbase = smem + MAXB;
    constexpr int T = 2048;
    for (int tile = bid; (long long)tile * T < E; tile += nblk) {
        int base = tile * T;
        for (int i = threadIdx.x; i < B; i += 256) lhist[i] = 0;
        __syncthreads();
        int sj0, sj1, sj2, sj3, sj4, sj5, sj6, sj7;
        int dj0, dj1, dj2, dj3, dj4, dj5, dj6, dj7;
        int rj0, rj1, rj2, rj3, rj4, rj5, rj6, rj7;
        int ej0, ej1, ej2, ej3, ej4, ej5, ej6, ej7;
        #define BINA_LOAD(J, SJ, DJ, RJ, EJ)                                   \
        {                                                                      \
            int idx = base + (J) * 256 + threadIdx.x;                          \
            bool v = idx < E;                                                  \
            int d = v ? clampi(dst[idx], 0, n - 1) : 0;                        \
            SJ = v ? clampi(src[idx], 0, n - 1) : 0;                           \
            EJ = v ? __float_as_int(load1(eattr, idx, f)) : 0;                 \
            DJ = d;                                                            \
            RJ = v ? atomicAdd(&lhist[d >> 8], 1) : -1;                        \
        }
        BINA_LOAD(0, sj0, dj0, rj0, ej0)
        BINA_LOAD(1, sj1, dj1, rj1, ej1)
        BINA_LOAD(2, sj2, dj2, rj2, ej2)
        BINA_LOAD(3, sj3, dj3, rj3, ej3)
        BINA_LOAD(4, sj4, dj4, rj4, ej4)
        BINA_LOAD(5, sj5, dj5, rj5, ej5)
        BINA_LOAD(6, sj6, dj6, rj6, ej6)
        BINA_LOAD(7, sj7, dj7, rj7, ej7)
        #undef BINA_LOAD
        __syncthreads();
        for (int i = threadIdx.x; i < B; i += 256) {
            int c = lhist[i];
            lbase[i] = c ? atomicAdd(&bfront[i], c) : 0;
        }
        __syncthreads();
        #define BINA_STORE(SJ, DJ, RJ, EJ)                                     \
        if (RJ >= 0) {                                                         \
            long long q = (long long)lbase[DJ >> 8] + RJ;                      \
            if (q >= 0 && q < E) {                                             \
                int2 v2;                                                       \
                v2.x = (SJ & 0xFFFFFF) | ((DJ & 255) << 24);                   \
                v2.y = EJ;                                                     \
                stagedA[q] = v2;                                               \
            }                                                                  \
        }
        BINA_STORE(sj0, dj0, rj0, ej0)
        BINA_STORE(sj1, dj1, rj1, ej1)
        BINA_STORE(sj2, dj2, rj2, ej2)
        BINA_STORE(sj3, dj3, rj3, ej3)
        BINA_STORE(sj4, dj4, rj4, ej4)
        BINA_STORE(sj5, dj5, rj5, ej5)
        BINA_STORE(sj6, dj6, rj6, ej6)
        BINA_STORE(sj7, dj7, rj7, ej7)
        #undef BINA_STORE
        __syncthreads();
    }
}

// ---------------- standalone GEMM wrapper ------------------------------------------------
template <int NC>
__global__ __launch_bounds__(256, 2) void k_gemm_mfma(
    const void* __restrict__ X, const void* __restrict__ Wg,
    const int* __restrict__ flag, int fXovr, u16* __restrict__ Y,
    const float* __restrict__ consts, float* __restrict__ casrc,
    float* __restrict__ cadst, int nrows) {
    __shared__ __align__(16) u16 Bf[2 * (NC / 16) * 4 * 64 * 8];
    const int f = *flag;
    dev_gemm<NC>(Bf, X, Wg, (fXovr < 0) ? (f != 0) : (fXovr != 0), f != 0,
                 Y, consts, casrc, cadst, nrows, blockIdx.x, gridDim.x);
}

// ---------------- FUSED launch: gemm128+coef1 (blocks < gb) || binA (blocks >= gb) ------
__global__ __launch_bounds__(256, 2) void k_fuse_gemm_binA(
    const void* __restrict__ X, const void* __restrict__ Wg,
    const int* __restrict__ flag, u16* __restrict__ Y,
    const float* __restrict__ consts, float* __restrict__ casrc,
    float* __restrict__ cadst, int nrows, int gemmBlocks,
    const int* __restrict__ dst, const int* __restrict__ src, const void* eattr,
    int* __restrict__ bfront, int2* __restrict__ stagedA, int E, int n, int B) {
    __shared__ __align__(16) char smem[2 * 8 * 4 * 64 * 8 * 2];  // 64KB (gemm128 Bf)
    const int f = *flag;
    if ((int)blockIdx.x < gemmBlocks) {
        dev_gemm<128>((u16*)smem, X, Wg, f != 0, f != 0, Y, consts, casrc, cadst,
                      nrows, blockIdx.x, gemmBlocks);
    } else {
        dev_binA((int*)smem, dst, src, eattr, f, bfront, stagedA, E, n, B,
                 blockIdx.x - gemmBlocks, gridDim.x - gemmBlocks);
    }
}

// ---------------- CSR build: fused hist + last-block scan --------------------------------
// Per-bucket LDS histogram -> bcnt atomics; last finishing block (done counter) performs
// the exclusive scan -> bbase/bfront and roff[N]=E. Saves the separate k_bscan launch.
__global__ __launch_bounds__(256) void k_bhist2b(const int* __restrict__ dst,
                                                 int* __restrict__ bcnt,
                                                 int* __restrict__ done,
                                                 int* __restrict__ bbase,
                                                 int* __restrict__ bfront,
                                                 int* __restrict__ roff,
                                                 int E, int n, int B, int N) {
    __shared__ int lh[MAXB];
    __shared__ int isLast;
    for (int i = threadIdx.x; i < B; i += 256) lh[i] = 0;
    __syncthreads();
    int stride = gridDim.x * 256;
    for (int e = blockIdx.x * 256 + threadIdx.x; e < E; e += stride) {
        int d = clampi(dst[e], 0, n - 1);
        atomicAdd(&lh[d >> 8], 1);
    }
    __syncthreads();
    for (int i = threadIdx.x; i < B; i += 256)
        if (lh[i]) atomicAdd(&bcnt[i], lh[i]);
    __threadfence();
    __syncthreads();
    if (threadIdx.x == 0) isLast = (atomicAdd(done, 1) == (int)gridDim.x - 1) ? 1 : 0;
    __syncthreads();
    if (!isLast) return;
    __threadfence();
    // ---- scan (reuse lh as scan buffer) ----
    __shared__ int buf[256];
    __shared__ int carry;
    int t = threadIdx.x;
    if (t == 0) carry = 0;
    __syncthreads();
    for (int base = 0; base < B; base += 256) {
        int k = base + t;
        int v = (k < B) ? bcnt[k] : 0;
        buf[t] = v;
        __syncthreads();
        for (int off = 1; off < 256; off <<= 1) {
            int u = (t >= off) ? buf[t - off] : 0;
            __syncthreads();
            buf[t] += u;
            __syncthreads();
        }
        int excl = carry + buf[t] - v;
        if (k < B) { bbase[k] = excl; bfront[k] = excl; }
        __syncthreads();
        if (t == 0) carry += buf[255];
        __syncthreads();
    }
    if (t == 0) { bbase[B] = carry; roff[N] = E; }
}
// ---- fallback-path CSR kernels ---------------------------------------------------------
__global__ void k_zero(int* __restrict__ p, int n) {
    int i = blockIdx.x * 256 + threadIdx.x;
    if (i < n) p[i] = 0;
}
__global__ __launch_bounds__(256) void k_bhist(const int* __restrict__ dst,
                                               int* __restrict__ cnt, int* __restrict__ bcnt,
                                               int E, int n, int B) {
    __shared__ int lh[MAXB];
    for (int i = threadIdx.x; i < B; i += 256) lh[i] = 0;
    __syncthreads();
    int stride = gridDim.x * 256;
    for (int e = blockIdx.x * 256 + threadIdx.x; e < E; e += stride) {
        int d = clampi(dst[e], 0, n - 1);
        atomicAdd(&cnt[d], 1);
        atomicAdd(&lh[d >> 8], 1);
    }
    __syncthreads();
    for (int i = threadIdx.x; i < B; i += 256)
        if (lh[i]) atomicAdd(&bcnt[i], lh[i]);
}
__global__ void k_scan1(const int* __restrict__ cnt, int* __restrict__ part,
                        int* __restrict__ bsum, int n) {
    __shared__ int buf[256];
    int i = blockIdx.x * 256 + threadIdx.x;
    int v = (i < n) ? cnt[i] : 0;
    buf[threadIdx.x] = v;
    __syncthreads();
    for (int off = 1; off < 256; off <<= 1) {
        int t = (threadIdx.x >= off) ? buf[threadIdx.x - off] : 0;
        __syncthreads();
        buf[threadIdx.x] += t;
        __syncthreads();
    }
    if (i < n) part[i] = buf[threadIdx.x];
    if (threadIdx.x == 255) bsum[blockIdx.x] = buf[255];
}
__global__ void k_scan3b(int* __restrict__ roff, const int* __restrict__ bsum,
                         int* __restrict__ rpos, int n, int nb) {
    __shared__ int buf[256];
    int t = threadIdx.x;
    int v = (t < nb) ? bsum[t] : 0;
    buf[t] = v;
    __syncthreads();
    for (int off = 1; off < 256; off <<= 1) {
        int u = (t >= off) ? buf[t - off] : 0;
        __syncthreads();
        buf[t] += u;
        __syncthreads();
    }
    __shared__ int excl[256];
    excl[t] = buf[t] - v;   // exclusive prefix of bsum
    __syncthreads();
    int i = blockIdx.x * 256 + t;
    if (i > n) return;
    int val;
    if (i == 0) { val = 0; roff[0] = 0; }
    else { val = roff[i] + excl[(i - 1) >> 8]; roff[i] = val; }
    if (i < n) rpos[i] = val;
}
// binB2: per bucket — pass1 count local nodes (LDS), scan 256 -> roff + scatter bases;
// pass2 pure streaming 8B permute.
__global__ __launch_bounds__(256) void k_binB2(
    const int2* __restrict__ stagedA, const int* __restrict__ bbase,
    int* __restrict__ roff, int2* __restrict__ edata, int N, int E, int B) {
    __shared__ int lcnt[256];
    __shared__ int buf[256];
    __shared__ int lpos[256];
    int k = blockIdx.x;
    int t = threadIdx.x;
    lcnt[t] = 0;
    __syncthreads();
    int lo = clampi(bbase[k], 0, E);
    int hi = clampi(bbase[k + 1], lo, E);
    for (int i = lo + t; i < hi; i += 256)
        atomicAdd(&lcnt[(stagedA[i].x >> 24) & 255], 1);
    __syncthreads();
    int v = lcnt[t];
    buf[t] = v;
    __syncthreads();
    for (int off = 1; off < 256; off <<= 1) {
        int u = (t >= off) ? buf[t - off] : 0;
        __syncthreads();
        buf[t] += u;
        __syncthreads();
    }
    int pos = lo + buf[t] - v;       // exclusive in-bucket prefix + bucket base
    int dn = (k << 8) + t;
    if (dn < N) roff[dn] = pos;
    lpos[t] = pos;
    __syncthreads();
    for (int i = lo + t; i < hi; i += 256) {
        int2 a = stagedA[i];
        int p = atomicAdd(&lpos[(a.x >> 24) & 255], 1);
        if (p >= 0 && p < E) edata[p] = make_int2(a.x & 0xFFFFFF, a.y);
    }
}
// fallback single-pass scatter
__global__ void k_scatter(const int* __restrict__ dst, const int* __restrict__ src,
                          const void* eattr, const int* __restrict__ flag,
                          int* __restrict__ rpos, int2* __restrict__ edata, int E, int n) {
    int f = *flag;
    int e = blockIdx.x * 256 + threadIdx.x;
    if (e < E) {
        int d = clampi(dst[e], 0, n - 1);
        int s = clampi(src[e], 0, n - 1);
        float ea = load1(eattr, e, f);
        int p = atomicAdd(&rpos[d], 1);
        if (p >= 0 && p < E) {
            int2 v; v.x = s; v.y = __float_as_int(ea);
            edata[p] = v;
        }
    }
}

// ---------------- gat1, CACHED: 2 nodes/wave, in-kernel exp, 4-edge unrolled gather -----
__global__ __launch_bounds__(256) void k_gat1c(
    const u32* __restrict__ hp, const float* __restrict__ asrc, const float* __restrict__ adst,
    const int2* __restrict__ edata, const int* __restrict__ roff,
    const int* __restrict__ flag, const float* __restrict__ consts, const void* bias,
    u32* __restrict__ out, int n, int E) {
    __shared__ float4 wls[4][64];
    int f = *flag;
    int gtid = blockIdx.x * 256 + threadIdx.x;
    int wv = gtid >> 6, lane = gtid & 63;
    int wid = (threadIdx.x >> 6);
    int nw = (gridDim.x * 256) >> 6;
    const float c0 = consts[0], c1 = consts[1], c2 = consts[2], c3 = consts[3];
    const int hl = lane & 31;          // half-lane
    const int sel = lane >> 5;         // which node of the pair
    const int p0 = hl * 2;             // owned u32 positions p0, p0+1
    const int phsel = hl >> 4;         // head selector for owned positions
    const float biasA0 = load1(bias, p0, f);
    const float biasB0 = load1(bias, 64 + p0, f);
    const float biasA1 = load1(bias, p0 + 1, f);
    const float biasB1 = load1(bias, 64 + p0 + 1, f);
    const int ghsel = lane >> 5;       // full-wave-path selectors
    const float gbiasA = load1(bias, lane, f);
    const float gbiasB = load1(bias, 64 + lane, f);

    for (int db = wv * 2; db < n; db += nw * 2) {
        int d = db + sel;
        bool dv = d < n;
        int dcl = dv ? d : 0;
        int s0 = dv ? clampi(roff[d], 0, E) : 0;
        int s1 = dv ? clampi(roff[d + 1], s0, E) : 0;
        int deg = s1 - s0;

        if (__all(deg <= 32)) {
            // ---- fast path: both nodes fit a half-wave ----
            float4 adv = *(const float4*)&adst[(size_t)dcl * 4];
            bool v = hl < deg;
            int s = 0;
            float e0 = 0.f, e1 = 0.f, e2 = 0.f, e3 = 0.f;
            if (v) {
                int2 ed = edata[s0 + hl];
                s = ed.x;
                float ea = __int_as_float(ed.y);
                float4 av = *(const float4*)&asrc[(size_t)s * 4];
                e0 = cexpf(lrelu(av.x + adv.x + ea * c0));
                e1 = cexpf(lrelu(av.y + adv.y + ea * c1));
                e2 = cexpf(lrelu(av.z + adv.z + ea * c2));
                e3 = cexpf(lrelu(av.w + adv.w + ea * c3));
            }
            float d0 = e0, d1 = e1, d2 = e2, d3 = e3;
            #pragma unroll
            for (int off = 16; off > 0; off >>= 1) {
                d0 += __shfl_xor(d0, off); d1 += __shfl_xor(d1, off);
                d2 += __shfl_xor(d2, off); d3 += __shfl_xor(d3, off);
            }
            float i0 = 1.f / (d0 + 1e-16f), i1 = 1.f / (d1 + 1e-16f);
            float i2 = 1.f / (d2 + 1e-16f), i3 = 1.f / (d3 + 1e-16f);
            wls[wid][lane] = make_float4(e0 * i0, e1 * i1, e2 * i2, e3 * i3); // 0 beyond deg

            int degm = max(deg, __shfl_xor(deg, 32));  // uniform loop bound, <= 32
            int base = sel * 32;
            float aA0 = 0.f, aB0 = 0.f, aA1 = 0.f, aB1 = 0.f;
            for (int j = 0; j < degm; j += 4) {
                int j0 = base + j, j1 = base + j + 1, j2 = base + j + 2, j3 = base + j + 3;
                int sa = __shfl(s, j0), sb = __shfl(s, j1);
                int sc_ = __shfl(s, j2), sd = __shfl(s, j3);
                float4 wa = wls[wid][j0], wb = wls[wid][j1];
                float4 wc = wls[wid][j2], wd = wls[wid][j3];
                uint2 ha = *(const uint2*)(hp + (size_t)sa * 64 + p0);
                uint2 hb = *(const uint2*)(hp + (size_t)sb * 64 + p0);
                uint2 hc = *(const uint2*)(hp + (size_t)sc_ * 64 + p0);
                uint2 hd = *(const uint2*)(hp + (size_t)sd * 64 + p0);
                float wAa = phsel ? wa.y : wa.x, wBa = phsel ? wa.w : wa.z;
                float wAb = phsel ? wb.y : wb.x, wBb = phsel ? wb.w : wb.z;
                float wAc = phsel ? wc.y : wc.x, wBc = phsel ? wc.w : wc.z;
                float wAd = phsel ? wd.y : wd.x, wBd = phsel ? wd.w : wd.z;
                aA0 += wAa * bl(ha.x); aB0 += wBa * bh(ha.x);
                aA1 += wAa * bl(ha.y); aB1 += wBa * bh(ha.y);
                aA0 += wAb * bl(hb.x); aB0 += wBb * bh(hb.x);
                aA1 += wAb * bl(hb.y); aB1 += wBb * bh(hb.y);
                aA0 += wAc * bl(hc.x); aB0 += wBc * bh(hc.x);
                aA1 += wAc * bl(hc.y); aB1 += wBc * bh(hc.y);
                aA0 += wAd * bl(hd.x); aB0 += wBd * bh(hd.x);
                aA1 += wAd * bl(hd.y); aB1 += wBd * bh(hd.y);
            }
            if (dv) {
                u32 w0 = (u32)f2bf(fmaxf(aA0 + biasA0, 0.f))
                       | ((u32)f2bf(fmaxf(aB0 + biasB0, 0.f)) << 16);
                u32 w1 = (u32)f2bf(fmaxf(aA1 + biasA1, 0.f))
                       | ((u32)f2bf(fmaxf(aB1 + biasB1, 0.f)) << 16);
                *(uint2*)(out + (size_t)d * 64 + p0) = make_uint2(w0, w1);
            }
        } else {
            // ---- fallback: process the pair sequentially with the full wave ----
            for (int q = 0; q < 2; q++) {
                int dq = db + q;
                if (dq >= n) break;
                int t0 = clampi(roff[dq], 0, E);
                int t1 = clampi(roff[dq + 1], t0, E);
                int dg = t1 - t0;
                float4 adv = *(const float4*)&adst[(size_t)dq * 4];
                if (dg <= 64) {
                    bool v = lane < dg;
                    int s = 0;
                    float e0 = 0.f, e1 = 0.f, e2 = 0.f, e3 = 0.f;
                    if (v) {
                        int2 ed = edata[t0 + lane];
                        s = ed.x;
                        float ea = __int_as_float(ed.y);
                        float4 av = *(const float4*)&asrc[(size_t)s * 4];
                        e0 = cexpf(lrelu(av.x + adv.x + ea * c0));
                        e1 = cexpf(lrelu(av.y + adv.y + ea * c1));
                        e2 = cexpf(lrelu(av.z + adv.z + ea * c2));
                        e3 = cexpf(lrelu(av.w + adv.w + ea * c3));
                    }
                    float d0 = e0, d1 = e1, d2 = e2, d3 = e3;
                    #pragma unroll
                    for (int off = 32; off > 0; off >>= 1) {
                        d0 += __shfl_xor(d0, off); d1 += __shfl_xor(d1, off);
                        d2 += __shfl_xor(d2, off); d3 += __shfl_xor(d3, off);
                    }
                    float i0 = 1.f / (d0 + 1e-16f), i1 = 1.f / (d1 + 1e-16f);
                    float i2 = 1.f / (d2 + 1e-16f), i3 = 1.f / (d3 + 1e-16f);
                    wls[wid][lane] = make_float4(e0 * i0, e1 * i1, e2 * i2, e3 * i3);

                    float aA0 = 0.f, aB0 = 0.f, aA1 = 0.f, aB1 = 0.f;
                    for (int j = 0; j < dg; j += 4) {
                        int j0 = j + sel, j1 = j + 2 + sel;
                        int sa = __shfl(s, j0), sb = __shfl(s, j1);
                        float4 wa = wls[wid][j0], wb = wls[wid][j1];
                        uint2 ha = *(const uint2*)(hp + (size_t)sa * 64 + p0);
                        uint2 hb = *(const uint2*)(hp + (size_t)sb * 64 + p0);
                        float wAa = phsel ? wa.y : wa.x, wBa = phsel ? wa.w : wa.z;
                        float wAb = phsel ? wb.y : wb.x, wBb = phsel ? wb.w : wb.z;
                        aA0 += wAa * bl(ha.x); aB0 += wBa * bh(ha.x);
                        aA1 += wAa * bl(ha.y); aB1 += wBa * bh(ha.y);
                        aA0 += wAb * bl(hb.x); aB0 += wBb * bh(hb.x);
                        aA1 += wAb * bl(hb.y); aB1 += wBb * bh(hb.y);
                    }
                    aA0 += __shfl_xor(aA0, 32); aB0 += __shfl_xor(aB0, 32);
                    aA1 += __shfl_xor(aA1, 32); aB1 += __shfl_xor(aB1, 32);
                    if (lane < 32) {
                        u32 w0 = (u32)f2bf(fmaxf(aA0 + biasA0, 0.f))
                               | ((u32)f2bf(fmaxf(aB0 + biasB0, 0.f)) << 16);
                        u32 w1 = (u32)f2bf(fmaxf(aA1 + biasA1, 0.f))
                               | ((u32)f2bf(fmaxf(aB1 + biasB1, 0.f)) << 16);
                        *(uint2*)(out + (size_t)dq * 64 + p0) = make_uint2(w0, w1);
                    }
                } else {
                    // general path: 2 passes (recompute exp in pass 2)
                    float d0 = 0.f, d1 = 0.f, d2 = 0.f, d3 = 0.f;
                    for (int idx = t0 + lane; idx < t1; idx += 64) {
                        int2 ed = edata[idx];
                        float ea = __int_as_float(ed.y);
                        float4 av = *(const float4*)&asrc[(size_t)ed.x * 4];
                        d0 += cexpf(lrelu(av.x + adv.x + ea * c0));
                        d1 += cexpf(lrelu(av.y + adv.y + ea * c1));
                        d2 += cexpf(lrelu(av.z + adv.z + ea * c2));
                        d3 += cexpf(lrelu(av.w + adv.w + ea * c3));
                    }
                    #pragma unroll
                    for (int off = 32; off > 0; off >>= 1) {
                        d0 += __shfl_xor(d0, off); d1 += __shfl_xor(d1, off);
                        d2 += __shfl_xor(d2, off); d3 += __shfl_xor(d3, off);
                    }
                    float i0 = 1.f / (d0 + 1e-16f), i1 = 1.f / (d1 + 1e-16f);
                    float i2 = 1.f / (d2 + 1e-16f), i3 = 1.f / (d3 + 1e-16f);
                    float iA = ghsel ? i1 : i0, iB = ghsel ? i3 : i2;
                    float cA = ghsel ? c1 : c0, cB = ghsel ? c3 : c2;
                    float aA = ghsel ? adv.y : adv.x, aB = ghsel ? adv.w : adv.z;
                    float accA = 0.f, accB = 0.f;
                    for (int idx = t0; idx < t1; idx++) {
                        int2 ed = edata[idx];
                        float ea = __int_as_float(ed.y);
                        float4 av = *(const float4*)&asrc[(size_t)ed.x * 4];
                        float wA = cexpf(lrelu((ghsel ? av.y : av.x) + aA + ea * cA)) * iA;
                        float wB = cexpf(lrelu((ghsel ? av.w : av.z) + aB + ea * cB)) * iB;
                        u32 hw = hp[(size_t)ed.x * 64 + lane];
                        accA += wA * bl(hw);
                        accB += wB * bh(hw);
                    }
                    float rA = fmaxf(accA + gbiasA, 0.f);
                    float rB = fmaxf(accB + gbiasB, 0.f);
                    out[(size_t)dq * 64 + lane] = (u32)f2bf(rA) | ((u32)f2bf(rB) << 16);
                }
            }
        }
    }
}

// ---------------- gat2, CACHED: 2 nodes/wave, 4-edge unrolled gather --------------------
__global__ __launch_bounds__(256) void k_gat2c(
    const u16* __restrict__ h, const float* __restrict__ asrc, const float* __restrict__ adst,
    const int2* __restrict__ edata, const int* __restrict__ roff,
    const int* __restrict__ flag, const float* __restrict__ consts, const void* bias,
    u16* __restrict__ out, int n, int E) {
    __shared__ float wls[4][64];
    int f = *flag;
    int gtid = blockIdx.x * 256 + threadIdx.x;
    int wv = gtid >> 6, lane = gtid & 63;
    int wid = (threadIdx.x >> 6);
    int nw = (gridDim.x * 256) >> 6;
    const float C = consts[4];
    const int hl = lane & 31;
    const int sel = lane >> 5;
    const int p0 = hl * 2;             // owned u16 pair (one u32)
    const float bias0 = load1(bias, p0, f);
    const float bias1 = load1(bias, p0 + 1, f);
    const float gbias = load1(bias, lane, f);

    for (int db = wv * 2; db < n; db += nw * 2) {
        int d = db + sel;
        bool dv = d < n;
        int s0 = dv ? clampi(roff[d], 0, E) : 0;
        int s1 = dv ? clampi(roff[d + 1], s0, E) : 0;
        int deg = s1 - s0;
        float ad = dv ? adst[d] : 0.f;

        if (__all(deg <= 32)) {
            bool v = hl < deg;
            int s = 0;
            float e = 0.f;
            if (v) {
                int2 ed = edata[s0 + hl];
                s = ed.x;
                e = cexpf(lrelu(asrc[s] + ad + __int_as_float(ed.y) * C));
            }
            float den = e;
            #pragma unroll
            for (int off = 16; off > 0; off >>= 1) den += __shfl_xor(den, off);
            float inv = 1.f / (den + 1e-16f);
            wls[wid][lane] = e * inv;                  // 0 beyond deg

            int degm = max(deg, __shfl_xor(deg, 32));
            int base = sel * 32;
            float a0 = 0.f, a1 = 0.f;
            for (int j = 0; j < degm; j += 4) {
                int j0 = base + j, j1 = base + j + 1, j2 = base + j + 2, j3 = base + j + 3;
                int sa = __shfl(s, j0), sb = __shfl(s, j1);
                int sc_ = __shfl(s, j2), sd = __shfl(s, j3);
                float wa = wls[wid][j0], wb = wls[wid][j1];
                float wc = wls[wid][j2], wd = wls[wid][j3];
                u32 ha = *(const u32*)(h + (size_t)sa * 64 + p0);
                u32 hb = *(const u32*)(h + (size_t)sb * 64 + p0);
                u32 hc = *(const u32*)(h + (size_t)sc_ * 64 + p0);
                u32 hd = *(const u32*)(h + (size_t)sd * 64 + p0);
                a0 += wa * bl(ha) + wb * bl(hb) + wc * bl(hc) + wd * bl(hd);
                a1 += wa * bh(ha) + wb * bh(hb) + wc * bh(hc) + wd * bh(hd);
            }
            if (dv) {
                u32 w = (u32)f2bf(a0 + bias0) | ((u32)f2bf(a1 + bias1) << 16);
                *(u32*)(out + (size_t)d * 64 + p0) = w;
            }
        } else {
            for (int q = 0; q < 2; q++) {
                int dq = db + q;
                if (dq >= n) break;
                int t0 = clampi(roff[dq], 0, E);
                int t1 = clampi(roff[dq + 1], t0, E);
                int dg = t1 - t0;
                float adq = adst[dq];
                if (dg <= 64) {
                    bool v = lane < dg;
                    int s = 0;
                    float e = 0.f;
                    if (v) {
                        int2 ed = edata[t0 + lane];
                        s = ed.x;
                        e = cexpf(lrelu(asrc[s] + adq + __int_as_float(ed.y) * C));
                    }
                    float den = e;
                    #pragma unroll
                    for (int off = 32; off > 0; off >>= 1) den += __shfl_xor(den, off);
                    float inv = 1.f / (den + 1e-16f);
                    wls[wid][lane] = e * inv;

                    float a0 = 0.f, a1 = 0.f;
                    for (int j = 0; j < dg; j += 4) {
                        int j0 = j + sel, j1 = j + 2 + sel;
                        int sa = __shfl(s, j0), sb = __shfl(s, j1);
                        float wa = wls[wid][j0], wb = wls[wid][j1];
                        u32 ha = *(const u32*)(h + (size_t)sa * 64 + p0);
                        u32 hb = *(const u32*)(h + (size_t)sb * 64 + p0);
                        a0 += wa * bl(ha) + wb * bl(hb);
                        a1 += wa * bh(ha) + wb * bh(hb);
                    }
                    a0 += __shfl_xor(a0, 32);
                    a1 += __shfl_xor(a1, 32);
                    if (lane < 32) {
                        u32 w = (u32)f2bf(a0 + bias0) | ((u32)f2bf(a1 + bias1) << 16);
                        *(u32*)(out + (size_t)dq * 64 + p0) = w;
                    }
                } else {
                    float den = 0.f;
                    for (int idx = t0 + lane; idx < t1; idx += 64) {
                        int2 ed = edata[idx];
                        den += cexpf(lrelu(asrc[ed.x] + adq + __int_as_float(ed.y) * C));
                    }
                    #pragma unroll
                    for (int off = 32; off > 0; off >>= 1) den += __shfl_xor(den, off);
                    float inv = 1.f / (den + 1e-16f);
                    float acc = 0.f;
                    for (int idx = t0; idx < t1; idx++) {
                        int2 ed = edata[idx];
                        float w = cexpf(lrelu(asrc[ed.x] + adq
                                              + __int_as_float(ed.y) * C)) * inv;
                        acc += w * bf2f(h[(size_t)ed.x * 64 + lane]);
                    }
                    out[(size_t)dq * 64 + lane] = f2bf(acc + gbias);
                }
            }
        }
    }
}

// ---------------- gat1/gat2 FALLBACK (recompute) ----------------------------------------
__global__ __launch_bounds__(256) void k_gat1f(
    const u32* __restrict__ hp, const float* __restrict__ asrc, const float* __restrict__ adst,
    const int2* __restrict__ edata, const int* __restrict__ roff,
    const int* __restrict__ flag, const float* __restrict__ consts, const void* bias,
    u32* __restrict__ out, int n, int E) {
    int f = *flag;
    int gtid = blockIdx.x * 256 + threadIdx.x;
    int wv = gtid >> 6, lane = gtid & 63;
    int nw = (gridDim.x * 256) >> 6;
    const float c0 = consts[0], c1 = consts[1], c2 = consts[2], c3 = consts[3];
    const int hsel = lane >> 5;
    const float biasA = load1(bias, lane, f);
    const float biasB = load1(bias, 64 + lane, f);

    for (int d = wv; d < n; d += nw) {
        int s0 = clampi(roff[d], 0, E);
        int s1 = clampi(roff[d + 1], s0, E);
        float4 adv = *(const float4*)&adst[d * 4];
        float d0 = 0.f, d1 = 0.f, d2 = 0.f, d3 = 0.f;
        for (int idx = s0 + lane; idx < s1; idx += 64) {
            int2 ed = edata[idx];
            float ea = __int_as_float(ed.y);
            float4 av = *(const float4*)&asrc[(size_t)ed.x * 4];
            d0 += cexpf(lrelu(av.x + adv.x + ea * c0));
            d1 += cexpf(lrelu(av.y + adv.y + ea * c1));
            d2 += cexpf(lrelu(av.z + adv.z + ea * c2));
            d3 += cexpf(lrelu(av.w + adv.w + ea * c3));
        }
        #pragma unroll
        for (int off = 32; off > 0; off >>= 1) {
            d0 += __shfl_xor(d0, off); d1 += __shfl_xor(d1, off);
            d2 += __shfl_xor(d2, off); d3 += __shfl_xor(d3, off);
        }
        float i0 = 1.f / (d0 + 1e-16f), i1 = 1.f / (d1 + 1e-16f);
        float i2 = 1.f / (d2 + 1e-16f), i3 = 1.f / (d3 + 1e-16f);
        float iA = hsel ? i1 : i0, iB = hsel ? i3 : i2;
        float cA = hsel ? c1 : c0, cB = hsel ? c3 : c2;
        float aA = hsel ? adv.y : adv.x, aB = hsel ? adv.w : adv.z;

        float accA = 0.f, accB = 0.f;
        for (int idx = s0; idx < s1; idx++) {
            int2 ed = edata[idx];
            float ea = __int_as_float(ed.y);
            float4 av = *(const float4*)&asrc[(size_t)ed.x * 4];
            float wA = cexpf(lrelu((hsel ? av.y : av.x) + aA + ea * cA)) * iA;
            float wB = cexpf(lrelu((hsel ? av.w : av.z) + aB + ea * cB)) * iB;
            u32 hw = hp[(size_t)ed.x * 64 + lane];
            accA += wA * bl(hw);
            accB += wB * bh(hw);
        }
        float rA = fmaxf(accA + biasA, 0.f);
        float rB = fmaxf(accB + biasB, 0.f);
        out[(size_t)d * 64 + lane] = (u32)f2bf(rA) | ((u32)f2bf(rB) << 16);
    }
}

__global__ __launch_bounds__(256) void k_gat2f(
    const u16* __restrict__ h, const float* __restrict__ asrc, const float* __restrict__ adst,
    const int2* __restrict__ edata, const int* __restrict__ roff,
    const int* __restrict__ flag, const float* __restrict__ consts, const void* bias,
    u16* __restrict__ out, int n, int E) {
    int f = *flag;
    int gtid = blockIdx.x * 256 + threadIdx.x;
    int wv = gtid >> 6, lane = gtid & 63;
    int nw = (gridDim.x * 256) >> 6;
    const float C = consts[4];
    const float biasL = load1(bias, lane, f);

    for (int d = wv; d < n; d += nw) {
        int s0 = clampi(roff[d], 0, E);
        int s1 = clampi(roff[d + 1], s0, E);
        float ad = adst[d];
        float den = 0.f;
        for (int idx = s0 + lane; idx < s1; idx += 64) {
            int2 ed = edata[idx];
            den += cexpf(lrelu(asrc[ed.x] + ad + __int_as_float(ed.y) * C));
        }
        #pragma unroll
        for (int off = 32; off > 0; off >>= 1) den += __shfl_xor(den, off);
        float inv = 1.f / (den + 1e-16f);

        float acc = 0.f;
        for (int idx = s0; idx < s1; idx++) {
            int2 ed = edata[idx];
            float w = cexpf(lrelu(asrc[ed.x] + ad + __int_as_float(ed.y) * C)) * inv;
            acc += w * bf2f(h[(size_t)ed.x * 64 + lane]);
        }
        out[(size_t)d * 64 + lane] = f2bf(acc + biasL);
    }
}

// ---------------- pooling + fused head (last-block pattern) -----------------------------
__global__ __launch_bounds__(256) void k_pool2h(
    const u16* __restrict__ agg2, const int* __restrict__ batch,
    float* __restrict__ pool, float* __restrict__ cnt, int n, int G, int rpb,
    int* __restrict__ done, const void* Wp, const void* bp,
    const int* __restrict__ flag, void* out) {
    __shared__ float lp[POOL_MAXG * 64];
    __shared__ float lc[POOL_MAXG];
    __shared__ int isLast;
    int t = threadIdx.x;
    for (int i = t; i < G * 64; i += 256) lp[i] = 0.f;
    for (int i = t; i < G; i += 256) lc[i] = 0.f;
    __syncthreads();
    int lane = t & 63;
    int rl = t >> 6;                      // row-lane 0..3
    int r0 = blockIdx.x * rpb;
    int r1 = min(r0 + rpb, n);
    float acc = 0.f, cacc = 0.f;
    int curg = -1;
    for (int j = r0 + rl; j < r1; j += 4) {
        int g = clampi(batch[j], 0, G - 1);
        float v = bf2f(agg2[(size_t)j * 64 + lane]);
        if (g != curg) {                  // rare: batch is sorted
            if (curg >= 0) {
                atomicAdd(&lp[curg * 64 + lane], acc);
                if (lane == 0) atomicAdd(&lc[curg], cacc);
            }
            acc = 0.f; cacc = 0.f; curg = g;
        }
        acc += v; cacc += 1.f;
    }
    if (curg >= 0) {
        atomicAdd(&lp[curg * 64 + lane], acc);
        if (lane == 0) atomicAdd(&lc[curg], cacc);
    }
    __syncthreads();
    for (int i = t; i < G * 64; i += 256) {
        float v = lp[i];
        if (v != 0.f) atomicAdd(&pool[i], v);
    }
    for (int i = t; i < G; i += 256) {
        float v = lc[i];
        if (v != 0.f) atomicAdd(&cnt[i], v);
    }
    __threadfence();
    __syncthreads();
    if (t == 0) isLast = (atomicAdd(done, 1) == (int)gridDim.x - 1) ? 1 : 0;
    __syncthreads();
    if (!isLast) return;
    __threadfence();
    // ---- head: last block computes the G outputs ----
    int f = *flag;
    int g = t;
    if (g < G) {
        float s = 0.f;
        for (int c = 0; c < 64; c++) s += pool[g * 64 + c] * load1(Wp, c, f);
        float cv = cnt[g];
        if (!(cv > 0.f)) cv = 1.f;
        float r = s / cv + load1(bp, 0, f);
        if (f) ((float*)out)[g] = r;
        else   ((u16*)out)[g] = f2bf(r);
    }
}

// fallback for G > POOL_MAXG
__global__ void k_pool(const u16* __restrict__ agg2, const int* __restrict__ batch,
                       float* __restrict__ pool, float* __restrict__ cnt, int n, int G) {
    int t = blockIdx.x * 256 + threadIdx.x;
    int nb8 = (n + 7) / 8;
    if (t >= nb8 * 64) return;
    int base = (t >> 6) * 8;
    int c = t & 63;
    int end = min(base + 8, n);
    float acc = 0.f, cacc = 0.f;
    int curg = clampi(batch[base], 0, G - 1);
    for (int j = base; j < end; j++) {
        int g = clampi(batch[j], 0, G - 1);
        if (g != curg) {
            atomicAdd(&pool[curg * 64 + c], acc);
            if (c == 0) atomicAdd(&cnt[curg], cacc);
            acc = 0.f; cacc = 0.f; curg = g;
        }
        acc += bf2f(agg2[(size_t)j * 64 + c]);
        cacc += 1.f;
    }
    atomicAdd(&pool[curg * 64 + c], acc);
    if (c == 0) atomicAdd(&cnt[curg], cacc);
}

__global__ void k_head(const float* __restrict__ pool, const float* __restrict__ cnt,
                       const void* Wp, const void* bp, const int* __restrict__ flag,
                       void* out, int G) {
    int f = *flag;
    int g = threadIdx.x;
    if (g >= G) return;
    float s = 0.f;
    for (int c = 0; c < 64; c++) s += pool[g * 64 + c] * load1(Wp, c, f);
    float cv = cnt[g];
    if (!(cv > 0.f)) cv = 1.f;
    float r = s / cv + load1(bp, 0, f);
    if (f) ((float*)out)[g] = r;
    else   ((u16*)out)[g] = f2bf(r);
}

// ---------------- launch ----------------------------------------------------------------
extern "C" void kernel_launch(void* const* d_in, const int* in_sizes, int n_in,
                              void* d_out, int out_size, void* d_ws, size_t ws_size,
                              hipStream_t stream) {
    const void* x    = d_in[0];
    const int* ei    = (const int*)d_in[1];
    const void* eattr = d_in[2];
    const int* batch = (const int*)d_in[3];
    const void* W1   = d_in[4];
    const void* as1  = d_in[5];
    const void* ad1  = d_in[6];
    const void* We1  = d_in[7];
    const void* ae1  = d_in[8];
    const void* b1   = d_in[9];
    const void* W2   = d_in[10];
    const void* as2  = d_in[11];
    const void* ad2  = d_in[12];
    const void* We2  = d_in[13];
    const void* ae2  = d_in[14];
    const void* b2   = d_in[15];
    const void* Wp   = d_in[16];
    const void* bp   = d_in[17];

    const int N = in_sizes[3];
    const int E = in_sizes[2];
    const int G = out_size;
    const int* src = ei;
    const int* dst = ei + E;
    const int B = (N + 255) >> 8;

    char* p = (char*)d_ws;
    auto alloc = [&](size_t bytes) -> char* {
        char* r = p;
        p += (bytes + 255) & ~(size_t)255;
        return r;
    };
    int* flag    = (int*)alloc(32);      // [0]=dtype, [1]=bhist done, [2]=pool done
    float* consts = (float*)alloc(2048);
    int* roff    = (int*)alloc((size_t)(N + 1) * 4);
    int* rpos    = (int*)alloc((size_t)N * 4);
    int* bsum    = (int*)alloc(256 * 4);
    int* bcnt    = (int*)alloc((size_t)(MAXB * 3 + 1) * 4);
    int* bbase   = bcnt + MAXB;          // B+1 entries
    int* bfront  = bbase + MAXB + 1;     // B entries
    int2* edata  = (int2*)alloc((size_t)E * 8);
    float* pool  = (float*)alloc((size_t)(G * 64 + G) * 4);
    float* cnt   = pool + (size_t)G * 64;
    float* asrc1 = (float*)alloc((size_t)N * 4 * 4);
    float* adst1 = (float*)alloc((size_t)N * 4 * 4);
    float* asrc2 = asrc1;             // alias: dead after gat1
    float* adst2 = adst1;
    u16* agg1    = (u16*)alloc((size_t)N * 128 * 2);
    u16* h1      = (u16*)alloc((size_t)N * 128 * 2);
    u16* h2      = h1;                // alias: h1 dead after gat1
    u16* agg2    = h1 + (size_t)N * 64;
    int2* stagedA = (int2*)alloc((size_t)E * 8);   // {src24|d8<<24, ea}
    size_t full_need = (size_t)(p - (char*)d_ws);
    const bool cached = (ws_size >= full_need);
    const bool binned = cached && (B <= MAXB) && (N <= (1 << 24));

    // GG = ceil(N/128): gemm handles tiles (bid, bid+GG); nBin = ceil(E/2048) binA blocks
    const int GG = (N + 127) >> 7;
    const int nBin = (E + 2047) / 2048;

    k_init<<<1, 256, 0, stream>>>((const u32*)x, flag, bcnt, B,
                                  We1, ae1, We2, ae2, as1, ad1, as2, ad2,
                                  consts, pool, G * 64 + G);

    if (binned) {
        // fused hist+scan (last-block), then FUSED gemm128 || binA overlap.
        k_bhist2b<<<512, 256, 0, stream>>>(dst, bcnt, flag + 1, bbase, bfront, roff,
                                           E, N, B, N);
        k_fuse_gemm_binA<<<GG + nBin, 256, 0, stream>>>(
            x, W1, flag, h1, consts, asrc1, adst1, N, GG,
            dst, src, eattr, bfront, stagedA, E, N, B);
        k_binB2<<<B, 256, 0, stream>>>(stagedA, bbase, roff, edata, N, E, B);
    } else {
        k_gemm_mfma<128><<<GG, 256, 0, stream>>>(x, W1, flag, -1, h1, consts,
                                                 asrc1, adst1, N);
        int NB = (N + 255) / 256;
        k_zero<<<(N + 255) / 256, 256, 0, stream>>>(rpos, N);
        k_bhist<<<512, 256, 0, stream>>>(dst, rpos, bcnt, E, N, B);
        k_scan1<<<NB, 256, 0, stream>>>(rpos, roff + 1, bsum, N);
        k_scan3b<<<(N + 256) / 256, 256, 0, stream>>>(roff, bsum, rpos, N, NB);
        k_scatter<<<(E + 255) / 256, 256, 0, stream>>>(dst, src, eattr, flag, rpos,
                                                       edata, E, N);
    }

    // right-sized gat grids: each block = 4 waves x 2 nodes = 8 nodes
    int gatBlocks = (N + 7) / 8;
    if (cached) {
        k_gat1c<<<gatBlocks, 256, 0, stream>>>((const u32*)h1, asrc1, adst1, edata, roff,
                                               flag, consts, b1, (u32*)agg1, N, E);
    } else {
        k_gat1f<<<gatBlocks, 256, 0, stream>>>((const u32*)h1, asrc1, adst1, edata, roff,
                                               flag, consts, b1, (u32*)agg1, N, E);
    }
    // gemm + fused coef2
    k_gemm_mfma<64><<<GG, 256, 0, stream>>>(agg1, W2, flag, 0, h2, consts,
                                            asrc2, adst2, N);
    if (cached) {
        k_gat2c<<<gatBlocks, 256, 0, stream>>>(h2, asrc2, adst2, edata, roff, flag,
                                               consts, b2, agg2, N, E);
    } else {
        k_gat2f<<<gatBlocks, 256, 0, stream>>>(h2, asrc2, adst2, edata, roff, flag,
                                               consts, b2, agg2, N, E);
    }
    if (G <= POOL_MAXG) {
        int rpb = (N + 1023) / 1024;
        if (rpb < 8) rpb = 8;
        int pblocks = (N + rpb - 1) / rpb;
        k_pool2h<<<pblocks, 256, 0, stream>>>(agg2, batch, pool, cnt, N, G, rpb,
                                              flag + 2, Wp, bp, flag, d_out);
    } else {
        k_pool<<<(((N + 7) / 8) * 64 + 255) / 256, 256, 0, stream>>>(agg2, batch, pool,
                                                                     cnt, N, G);
        k_head<<<1, 64, 0, stream>>>(pool, cnt, Wp, bp, flag, d_out, G);
    }
}

// Round 12
// 258.165 us; speedup vs baseline: 1.2856x; 1.2856x over previous
//
#include <hip/hip_runtime.h>
#include <hip/hip_bf16.h>

typedef unsigned short u16;
typedef unsigned int u32;

#define MAXB 2048
#define POOL_MAXG 64

typedef __attribute__((ext_vector_type(8))) short bf16x8;
typedef __attribute__((ext_vector_type(4))) float f32x4;

__device__ __forceinline__ float bf2f(u16 u) { return __uint_as_float(((u32)u) << 16); }
__device__ __forceinline__ float bl(u32 u) { return __uint_as_float(u << 16); }
__device__ __forceinline__ float bh(u32 u) { return __uint_as_float(u & 0xffff0000u); }
__device__ __forceinline__ u16 f2bf(float f) {
    u32 u = __float_as_uint(f);
    u += 0x7fffu + ((u >> 16) & 1u);   // round-to-nearest-even
    return (u16)(u >> 16);
}
__device__ __forceinline__ float lrelu(float x) { return x > 0.f ? x : 0.2f * x; }
__device__ __forceinline__ int clampi(int v, int lo, int hi) {
    return v < lo ? lo : (v > hi ? hi : v);
}
__device__ __forceinline__ float load1(const void* base, int idx, int f32) {
    return f32 ? ((const float*)base)[idx] : bf2f(((const u16*)base)[idx]);
}
// softmax without max-shift: clamp keeps exp finite; shift-invariance => same ratios.
__device__ __forceinline__ float cexpf(float a) {
    return __builtin_amdgcn_exp2f(fminf(a, 30.f) * 1.4426950408889634f);
}

// ---------------- init: dtype detect + consts + zero bcnt/pool (merged) -----------------
__global__ void k_init(const u32* __restrict__ xw, int* __restrict__ flag,
                       int* __restrict__ bcnt, int B,
                       const void* We1, const void* ae1, const void* We2, const void* ae2,
                       const void* as1, const void* ad1, const void* as2, const void* ad2,
                       float* __restrict__ consts, float* __restrict__ pool, int psize) {
    __shared__ int sf;
    int t = threadIdx.x;
    for (int i = t; i < B; i += 256) bcnt[i] = 0;
    if (t < 64) {
        int cnt = 0;
        #pragma unroll
        for (int j = 0; j < 4; j++) {
            u32 w = xw[t * 4 + j];
            int e0 = (int)((w >> 7) & 0xffu);
            int e1 = (int)((w >> 23) & 0xffu);
            cnt += (e0 >= 0x60 && e0 <= 0x8f);
            cnt += (e1 >= 0x60 && e1 <= 0x8f);
        }
        #pragma unroll
        for (int off = 32; off > 0; off >>= 1) cnt += __shfl_xor(cnt, off);
        if (t == 0) { int v = (cnt < 480) ? 1 : 0; *flag = v; sf = v; }
    }
    __syncthreads();
    int f = sf;
    for (int i = t; i < psize; i += 256) pool[i] = 0.f;
    if (t < 4) {
        float s = 0.f;
        for (int c = 0; c < 32; c++) s += load1(We1, t * 32 + c, f) * load1(ae1, t * 32 + c, f);
        consts[t] = s;
    } else if (t == 4) {
        float s = 0.f;
        for (int c = 0; c < 64; c++) s += load1(We2, c, f) * load1(ae2, c, f);
        consts[4] = s;
    }
    if (t < 128) {
        consts[8 + t] = load1(as1, t, f);
        consts[136 + t] = load1(ad1, t, f);
    }
    if (t < 64) {
        consts[264 + t] = load1(as2, t, f);
        consts[328 + t] = load1(ad2, t, f);
    }
}

// ---------------- GEMM device body: 2 tiles/block concurrent + fused coef epilogue -------
template <int NC>
__device__ __forceinline__ void dev_gemm(
    u16* __restrict__ Bf,   // LDS arena: 2*(NC/16)*4*64*8 u16
    const void* __restrict__ X, const void* __restrict__ Wg, bool fX, bool fW,
    u16* __restrict__ Y, const float* __restrict__ consts,
    float* __restrict__ casrc, float* __restrict__ cadst,
    int nrows, int bid, int nblocks) {
    constexpr int NCT = NC / 16;
    const int tid = threadIdx.x;
    const int wid = tid >> 6, lane = tid & 63;
    auto bfi = [&](int hh, int t, int s, int l, int j) {
        return ((((hh)*NCT + t) * 4 + s) * 64 + l) * 8 + j;
    };

    // ---- stage W -> LDS (coalesced global reads, scattered 2B LDS writes) ----
    if (fW) {
        const float* W4 = (const float*)Wg;
        for (int g = tid; g < 128 * NC / 4; g += 256) {
            int e = g * 4;
            int r = e / NC;
            int c = e % NC;
            int k = (NC == 64) ? ((r < 64) ? 2 * r : 2 * (r - 64) + 1) : r;
            int s = k >> 5;
            int kk = k & 31;
            int lhi = (kk >> 3) << 4;
            int j = kk & 7;
            float4 v = *(const float4*)(W4 + e);
            float vv[4] = {v.x, v.y, v.z, v.w};
            #pragma unroll
            for (int q = 0; q < 4; q++) {
                int col = c + q;
                int t = col >> 4, l = lhi | (col & 15);
                u16 h = f2bf(vv[q]);
                Bf[bfi(0, t, s, l, j)] = h;
                Bf[bfi(1, t, s, l, j)] = f2bf(vv[q] - bf2f(h));
            }
        }
    } else {
        const u16* Wb = (const u16*)Wg;
        for (int g = tid; g < 128 * NC / 8; g += 256) {
            int e = g * 8;
            int r = e / NC;
            int c = e % NC;
            int k = (NC == 64) ? ((r < 64) ? 2 * r : 2 * (r - 64) + 1) : r;
            int s = k >> 5;
            int kk = k & 31;
            int lhi = (kk >> 3) << 4;
            int j = kk & 7;
            uint4 v = *(const uint4*)(Wb + e);
            u16 arr[8] = {(u16)v.x, (u16)(v.x >> 16), (u16)v.y, (u16)(v.y >> 16),
                          (u16)v.z, (u16)(v.z >> 16), (u16)v.w, (u16)(v.w >> 16)};
            #pragma unroll
            for (int q = 0; q < 8; q++) {
                int col = c + q;
                int t = col >> 4, l = lhi | (col & 15);
                Bf[bfi(0, t, s, l, j)] = arr[q];
            }
        }
    }
    __syncthreads();

    const int tileIds[2] = {bid, bid + nblocks};

    // ---- A fragments for BOTH tiles: all loads issued together ----
    bf16x8 ahi[2][4], alo[2][4];
    #pragma unroll
    for (int tt = 0; tt < 2; tt++) {
        const int rowbase = tileIds[tt] * 64 + wid * 16;
        const int arow = rowbase + (lane & 15);
        const bool rv = arow < nrows;
        #pragma unroll
        for (int s = 0; s < 4; s++) {
            int koff = s * 32 + (lane >> 4) * 8;
            u16 h[8], l8[8];
            #pragma unroll
            for (int j = 0; j < 8; j++) { h[j] = 0; l8[j] = 0; }
            if (rv) {
                if (fX) {
                    const float* xp = (const float*)X + (size_t)arow * 128 + koff;
                    float4 a = *(const float4*)xp;
                    float4 b = *(const float4*)(xp + 4);
                    float vv[8];
                    vv[0] = a.x; vv[1] = a.y; vv[2] = a.z; vv[3] = a.w;
                    vv[4] = b.x; vv[5] = b.y; vv[6] = b.z; vv[7] = b.w;
                    #pragma unroll
                    for (int j = 0; j < 8; j++) {
                        h[j] = f2bf(vv[j]);
                        l8[j] = f2bf(vv[j] - bf2f(h[j]));
                    }
                } else {
                    const u16* xp = (const u16*)X + (size_t)arow * 128 + koff;
                    uint4 q = *(const uint4*)xp;
                    h[0] = (u16)q.x; h[1] = (u16)(q.x >> 16);
                    h[2] = (u16)q.y; h[3] = (u16)(q.y >> 16);
                    h[4] = (u16)q.z; h[5] = (u16)(q.z >> 16);
                    h[6] = (u16)q.w; h[7] = (u16)(q.w >> 16);
                }
            }
            bf16x8 vh, vl;
            #pragma unroll
            for (int j = 0; j < 8; j++) { vh[j] = (short)h[j]; vl[j] = (short)l8[j]; }
            ahi[tt][s] = vh; alo[tt][s] = vl;
        }
    }

    // ---- MFMA: each B-frag read feeds both tiles ----
    f32x4 acc[2][NCT];
    #pragma unroll
    for (int tt = 0; tt < 2; tt++)
        #pragma unroll
        for (int t = 0; t < NCT; t++) acc[tt][t] = (f32x4){0.f, 0.f, 0.f, 0.f};
    #pragma unroll
    for (int s = 0; s < 4; s++) {
        #pragma unroll
        for (int t = 0; t < NCT; t++) {
            bf16x8 bhi = *(const bf16x8*)(Bf + bfi(0, t, s, lane, 0));
            acc[0][t] = __builtin_amdgcn_mfma_f32_16x16x32_bf16(ahi[0][s], bhi, acc[0][t], 0, 0, 0);
            acc[1][t] = __builtin_amdgcn_mfma_f32_16x16x32_bf16(ahi[1][s], bhi, acc[1][t], 0, 0, 0);
            if (fW) {
                bf16x8 blo = *(const bf16x8*)(Bf + bfi(1, t, s, lane, 0));
                acc[0][t] = __builtin_amdgcn_mfma_f32_16x16x32_bf16(ahi[0][s], blo, acc[0][t], 0, 0, 0);
                acc[1][t] = __builtin_amdgcn_mfma_f32_16x16x32_bf16(ahi[1][s], blo, acc[1][t], 0, 0, 0);
            }
            if (fX) {
                acc[0][t] = __builtin_amdgcn_mfma_f32_16x16x32_bf16(alo[0][s], bhi, acc[0][t], 0, 0, 0);
                acc[1][t] = __builtin_amdgcn_mfma_f32_16x16x32_bf16(alo[1][s], bhi, acc[1][t], 0, 0, 0);
            }
        }
    }

    // ---- store + fused coef epilogue, per tile ----
    #pragma unroll
    for (int tt = 0; tt < 2; tt++) {
        const int rowbase = tileIds[tt] * 64 + wid * 16;
        const int l16 = lane & 15;
        #pragma unroll
        for (int reg = 0; reg < 4; reg++) {
            int r = rowbase + (lane >> 4) * 4 + reg;
            if (r < nrows) {
                if constexpr (NC == 128) {
                    #pragma unroll
                    for (int t = 0; t < 4; t++) {
                        u32 w = (u32)f2bf(acc[tt][t][reg])
                              | ((u32)f2bf(acc[tt][t + 4][reg]) << 16);
                        ((u32*)Y)[(size_t)r * 64 + t * 16 + l16] = w;
                    }
                } else {
                    #pragma unroll
                    for (int t = 0; t < 4; t++)
                        Y[(size_t)r * 64 + t * 16 + l16] = f2bf(acc[tt][t][reg]);
                }
            }
        }
        if (casrc) {
            if constexpr (NC == 128) {
                #pragma unroll
                for (int reg = 0; reg < 4; reg++) {
                    int r = rowbase + (lane >> 4) * 4 + reg;
                    float pA[4] = {0.f, 0.f, 0.f, 0.f};
                    float pD[4] = {0.f, 0.f, 0.f, 0.f};
                    #pragma unroll
                    for (int t = 0; t < 4; t++) {
                        int p = t * 16 + l16;
                        int g = t >> 1;
                        pA[g]     += acc[tt][t][reg]     * consts[8 + p];
                        pD[g]     += acc[tt][t][reg]     * consts[136 + p];
                        pA[g + 2] += acc[tt][t + 4][reg] * consts[72 + p];
                        pD[g + 2] += acc[tt][t + 4][reg] * consts[200 + p];
                    }
                    #pragma unroll
                    for (int off = 1; off < 16; off <<= 1) {
                        #pragma unroll
                        for (int g = 0; g < 4; g++) {
                            pA[g] += __shfl_xor(pA[g], off);
                            pD[g] += __shfl_xor(pD[g], off);
                        }
                    }
                    if (l16 == 0 && r < nrows) {
                        #pragma unroll
                        for (int g = 0; g < 4; g++) {
                            casrc[r * 4 + g] = pA[g];
                            cadst[r * 4 + g] = pD[g];
                        }
                    }
                }
            } else {
                #pragma unroll
                for (int reg = 0; reg < 4; reg++) {
                    int r = rowbase + (lane >> 4) * 4 + reg;
                    float s1 = 0.f, s2 = 0.f;
                    #pragma unroll
                    for (int t = 0; t < 4; t++) {
                        int p = t * 16 + l16;
                        s1 += acc[tt][t][reg] * consts[264 + p];
                        s2 += acc[tt][t][reg] * consts[328 + p];
                    }
                    #pragma unroll
                    for (int off = 1; off < 16; off <<= 1) {
                        s1 += __shfl_xor(s1, off);
                        s2 += __shfl_xor(s2, off);
                    }
                    if (l16 == 0 && r < nrows) { casrc[r] = s1; cadst[r] = s2; }
                }
            }
        }
    }
}

// ---------------- binA device body: tile-ranked bucket scatter -> stagedA ---------------
__device__ __forceinline__ void dev_binA(
    int* __restrict__ smem,   // LDS arena: lhist[MAXB], lbase[MAXB]
    const int* __restrict__ dst, const int* __restrict__ src, const void* eattr,
    int f, int* __restrict__ bfront, int2* __restrict__ stagedA,
    int E, int n, int B, int bid, int nblk) {
    int* lhist = smem;
    int* lbase = smem + MAXB;
    constexpr int T = 2048;
    for (int tile = bid; (long long)tile * T < E; tile += nblk) {
        int base = tile * T;
        for (int i = threadIdx.x; i < B; i += 256) lhist[i] = 0;
        __syncthreads();
        int sj0, sj1, sj2, sj3, sj4, sj5, sj6, sj7;
        int dj0, dj1, dj2, dj3, dj4, dj5, dj6, dj7;
        int rj0, rj1, rj2, rj3, rj4, rj5, rj6, rj7;
        int ej0, ej1, ej2, ej3, ej4, ej5, ej6, ej7;
        #define BINA_LOAD(J, SJ, DJ, RJ, EJ)                                   \
        {                                                                      \
            int idx = base + (J) * 256 + threadIdx.x;                          \
            bool v = idx < E;                                                  \
            int d = v ? clampi(dst[idx], 0, n - 1) : 0;                        \
            SJ = v ? clampi(src[idx], 0, n - 1) : 0;                           \
            EJ = v ? __float_as_int(load1(eattr, idx, f)) : 0;                 \
            DJ = d;                                                            \
            RJ = v ? atomicAdd(&lhist[d >> 8], 1) : -1;                        \
        }
        BINA_LOAD(0, sj0, dj0, rj0, ej0)
        BINA_LOAD(1, sj1, dj1, rj1, ej1)
        BINA_LOAD(2, sj2, dj2, rj2, ej2)
        BINA_LOAD(3, sj3, dj3, rj3, ej3)
        BINA_LOAD(4, sj4, dj4, rj4, ej4)
        BINA_LOAD(5, sj5, dj5, rj5, ej5)
        BINA_LOAD(6, sj6, dj6, rj6, ej6)
        BINA_LOAD(7, sj7, dj7, rj7, ej7)
        #undef BINA_LOAD
        __syncthreads();
        for (int i = threadIdx.x; i < B; i += 256) {
            int c = lhist[i];
            lbase[i] = c ? atomicAdd(&bfront[i], c) : 0;
        }
        __syncthreads();
        #define BINA_STORE(SJ, DJ, RJ, EJ)                                     \
        if (RJ >= 0) {                                                         \
            long long q = (long long)lbase[DJ >> 8] + RJ;                      \
            if (q >= 0 && q < E) {                                             \
                int2 v2;                                                       \
                v2.x = (SJ & 0xFFFFFF) | ((DJ & 255) << 24);                   \
                v2.y = EJ;                                                     \
                stagedA[q] = v2;                                               \
            }                                                                  \
        }
        BINA_STORE(sj0, dj0, rj0, ej0)
        BINA_STORE(sj1, dj1, rj1, ej1)
        BINA_STORE(sj2, dj2, rj2, ej2)
        BINA_STORE(sj3, dj3, rj3, ej3)
        BINA_STORE(sj4, dj4, rj4, ej4)
        BINA_STORE(sj5, dj5, rj5, ej5)
        BINA_STORE(sj6, dj6, rj6, ej6)
        BINA_STORE(sj7, dj7, rj7, ej7)
        #undef BINA_STORE
        __syncthreads();
    }
}

// ---------------- standalone GEMM wrapper ------------------------------------------------
template <int NC>
__global__ __launch_bounds__(256, 2) void k_gemm_mfma(
    const void* __restrict__ X, const void* __restrict__ Wg,
    const int* __restrict__ flag, int fXovr, u16* __restrict__ Y,
    const float* __restrict__ consts, float* __restrict__ casrc,
    float* __restrict__ cadst, int nrows) {
    __shared__ __align__(16) u16 Bf[2 * (NC / 16) * 4 * 64 * 8];
    const int f = *flag;
    dev_gemm<NC>(Bf, X, Wg, (fXovr < 0) ? (f != 0) : (fXovr != 0), f != 0,
                 Y, consts, casrc, cadst, nrows, blockIdx.x, gridDim.x);
}

// ---------------- FUSED launch: gemm128+coef1 (blocks < gb) || binA (blocks >= gb) ------
__global__ __launch_bounds__(256, 2) void k_fuse_gemm_binA(
    const void* __restrict__ X, const void* __restrict__ Wg,
    const int* __restrict__ flag, u16* __restrict__ Y,
    const float* __restrict__ consts, float* __restrict__ casrc,
    float* __restrict__ cadst, int nrows, int gemmBlocks,
    const int* __restrict__ dst, const int* __restrict__ src, const void* eattr,
    int* __restrict__ bfront, int2* __restrict__ stagedA, int E, int n, int B) {
    __shared__ __align__(16) char smem[2 * 8 * 4 * 64 * 8 * 2];  // 64KB (gemm128 Bf)
    const int f = *flag;
    if ((int)blockIdx.x < gemmBlocks) {
        dev_gemm<128>((u16*)smem, X, Wg, f != 0, f != 0, Y, consts, casrc, cadst,
                      nrows, blockIdx.x, gemmBlocks);
    } else {
        dev_binA((int*)smem, dst, src, eattr, f, bfront, stagedA, E, n, B,
                 blockIdx.x - gemmBlocks, gridDim.x - gemmBlocks);
    }
}

// ---------------- CSR build -------------------------------------------------------------
__global__ __launch_bounds__(256) void k_bhist2(const int* __restrict__ dst,
                                                int* __restrict__ bcnt, int E, int n, int B) {
    __shared__ int lh[MAXB];
    for (int i = threadIdx.x; i < B; i += 256) lh[i] = 0;
    __syncthreads();
    int stride = gridDim.x * 256;
    for (int e = blockIdx.x * 256 + threadIdx.x; e < E; e += stride) {
        int d = clampi(dst[e], 0, n - 1);
        atomicAdd(&lh[d >> 8], 1);
    }
    __syncthreads();
    for (int i = threadIdx.x; i < B; i += 256)
        if (lh[i]) atomicAdd(&bcnt[i], lh[i]);
}
__global__ void k_bscan(const int* __restrict__ bcnt, int* __restrict__ bbase,
                        int* __restrict__ bfront, int* __restrict__ roff,
                        int B, int N, int E) {
    __shared__ int buf[256];
    __shared__ int carry;
    int t = threadIdx.x;
    if (t == 0) carry = 0;
    __syncthreads();
    for (int base = 0; base < B; base += 256) {
        int k = base + t;
        int v = (k < B) ? bcnt[k] : 0;
        buf[t] = v;
        __syncthreads();
        for (int off = 1; off < 256; off <<= 1) {
            int u = (t >= off) ? buf[t - off] : 0;
            __syncthreads();
            buf[t] += u;
            __syncthreads();
        }
        int excl = carry + buf[t] - v;
        if (k < B) { bbase[k] = excl; bfront[k] = excl; }
        __syncthreads();
        if (t == 0) carry += buf[255];
        __syncthreads();
    }
    if (t == 0) { bbase[B] = carry; roff[N] = E; }
}
// ---- fallback-path CSR kernels ---------------------------------------------------------
__global__ void k_zero(int* __restrict__ p, int n) {
    int i = blockIdx.x * 256 + threadIdx.x;
    if (i < n) p[i] = 0;
}
__global__ __launch_bounds__(256) void k_bhist(const int* __restrict__ dst,
                                               int* __restrict__ cnt, int* __restrict__ bcnt,
                                               int E, int n, int B) {
    __shared__ int lh[MAXB];
    for (int i = threadIdx.x; i < B; i += 256) lh[i] = 0;
    __syncthreads();
    int stride = gridDim.x * 256;
    for (int e = blockIdx.x * 256 + threadIdx.x; e < E; e += stride) {
        int d = clampi(dst[e], 0, n - 1);
        atomicAdd(&cnt[d], 1);
        atomicAdd(&lh[d >> 8], 1);
    }
    __syncthreads();
    for (int i = threadIdx.x; i < B; i += 256)
        if (lh[i]) atomicAdd(&bcnt[i], lh[i]);
}
__global__ void k_scan1(const int* __restrict__ cnt, int* __restrict__ part,
                        int* __restrict__ bsum, int n) {
    __shared__ int buf[256];
    int i = blockIdx.x * 256 + threadIdx.x;
    int v = (i < n) ? cnt[i] : 0;
    buf[threadIdx.x] = v;
    __syncthreads();
    for (int off = 1; off < 256; off <<= 1) {
        int t = (threadIdx.x >= off) ? buf[threadIdx.x - off] : 0;
        __syncthreads();
        buf[threadIdx.x] += t;
        __syncthreads();
    }
    if (i < n) part[i] = buf[threadIdx.x];
    if (threadIdx.x == 255) bsum[blockIdx.x] = buf[255];
}
__global__ void k_scan3b(int* __restrict__ roff, const int* __restrict__ bsum,
                         int* __restrict__ rpos, int n, int nb) {
    __shared__ int buf[256];
    int t = threadIdx.x;
    int v = (t < nb) ? bsum[t] : 0;
    buf[t] = v;
    __syncthreads();
    for (int off = 1; off < 256; off <<= 1) {
        int u = (t >= off) ? buf[t - off] : 0;
        __syncthreads();
        buf[t] += u;
        __syncthreads();
    }
    __shared__ int excl[256];
    excl[t] = buf[t] - v;   // exclusive prefix of bsum
    __syncthreads();
    int i = blockIdx.x * 256 + t;
    if (i > n) return;
    int val;
    if (i == 0) { val = 0; roff[0] = 0; }
    else { val = roff[i] + excl[(i - 1) >> 8]; roff[i] = val; }
    if (i < n) rpos[i] = val;
}
// binB2: per bucket — pass1 count local nodes (LDS), scan 256 -> roff + scatter bases;
// pass2 pure streaming 8B permute.
__global__ __launch_bounds__(256) void k_binB2(
    const int2* __restrict__ stagedA, const int* __restrict__ bbase,
    int* __restrict__ roff, int2* __restrict__ edata, int N, int E, int B) {
    __shared__ int lcnt[256];
    __shared__ int buf[256];
    __shared__ int lpos[256];
    int k = blockIdx.x;
    int t = threadIdx.x;
    lcnt[t] = 0;
    __syncthreads();
    int lo = clampi(bbase[k], 0, E);
    int hi = clampi(bbase[k + 1], lo, E);
    for (int i = lo + t; i < hi; i += 256)
        atomicAdd(&lcnt[(stagedA[i].x >> 24) & 255], 1);
    __syncthreads();
    int v = lcnt[t];
    buf[t] = v;
    __syncthreads();
    for (int off = 1; off < 256; off <<= 1) {
        int u = (t >= off) ? buf[t - off] : 0;
        __syncthreads();
        buf[t] += u;
        __syncthreads();
    }
    int pos = lo + buf[t] - v;       // exclusive in-bucket prefix + bucket base
    int dn = (k << 8) + t;
    if (dn < N) roff[dn] = pos;
    lpos[t] = pos;
    __syncthreads();
    for (int i = lo + t; i < hi; i += 256) {
        int2 a = stagedA[i];
        int p = atomicAdd(&lpos[(a.x >> 24) & 255], 1);
        if (p >= 0 && p < E) edata[p] = make_int2(a.x & 0xFFFFFF, a.y);
    }
}
// fallback single-pass scatter
__global__ void k_scatter(const int* __restrict__ dst, const int* __restrict__ src,
                          const void* eattr, const int* __restrict__ flag,
                          int* __restrict__ rpos, int2* __restrict__ edata, int E, int n) {
    int f = *flag;
    int e = blockIdx.x * 256 + threadIdx.x;
    if (e < E) {
        int d = clampi(dst[e], 0, n - 1);
        int s = clampi(src[e], 0, n - 1);
        float ea = load1(eattr, e, f);
        int p = atomicAdd(&rpos[d], 1);
        if (p >= 0 && p < E) {
            int2 v; v.x = s; v.y = __float_as_int(ea);
            edata[p] = v;
        }
    }
}

// ---------------- gat1, CACHED: 2 nodes/wave, in-kernel exp, 4-edge unrolled gather -----
__global__ __launch_bounds__(256) void k_gat1c(
    const u32* __restrict__ hp, const float* __restrict__ asrc, const float* __restrict__ adst,
    const int2* __restrict__ edata, const int* __restrict__ roff,
    const int* __restrict__ flag, const float* __restrict__ consts, const void* bias,
    u32* __restrict__ out, int n, int E) {
    __shared__ float4 wls[4][64];
    int f = *flag;
    int gtid = blockIdx.x * 256 + threadIdx.x;
    int wv = gtid >> 6, lane = gtid & 63;
    int wid = (threadIdx.x >> 6);
    int nw = (gridDim.x * 256) >> 6;
    const float c0 = consts[0], c1 = consts[1], c2 = consts[2], c3 = consts[3];
    const int hl = lane & 31;          // half-lane
    const int sel = lane >> 5;         // which node of the pair
    const int p0 = hl * 2;             // owned u32 positions p0, p0+1
    const int phsel = hl >> 4;         // head selector for owned positions
    const float biasA0 = load1(bias, p0, f);
    const float biasB0 = load1(bias, 64 + p0, f);
    const float biasA1 = load1(bias, p0 + 1, f);
    const float biasB1 = load1(bias, 64 + p0 + 1, f);
    const int ghsel = lane >> 5;       // full-wave-path selectors
    const float gbiasA = load1(bias, lane, f);
    const float gbiasB = load1(bias, 64 + lane, f);

    for (int db = wv * 2; db < n; db += nw * 2) {
        int d = db + sel;
        bool dv = d < n;
        int dcl = dv ? d : 0;
        int s0 = dv ? clampi(roff[d], 0, E) : 0;
        int s1 = dv ? clampi(roff[d + 1], s0, E) : 0;
        int deg = s1 - s0;

        if (__all(deg <= 32)) {
            // ---- fast path: both nodes fit a half-wave ----
            float4 adv = *(const float4*)&adst[(size_t)dcl * 4];
            bool v = hl < deg;
            int s = 0;
            float e0 = 0.f, e1 = 0.f, e2 = 0.f, e3 = 0.f;
            if (v) {
                int2 ed = edata[s0 + hl];
                s = ed.x;
                float ea = __int_as_float(ed.y);
                float4 av = *(const float4*)&asrc[(size_t)s * 4];
                e0 = cexpf(lrelu(av.x + adv.x + ea * c0));
                e1 = cexpf(lrelu(av.y + adv.y + ea * c1));
                e2 = cexpf(lrelu(av.z + adv.z + ea * c2));
                e3 = cexpf(lrelu(av.w + adv.w + ea * c3));
            }
            float d0 = e0, d1 = e1, d2 = e2, d3 = e3;
            #pragma unroll
            for (int off = 16; off > 0; off >>= 1) {
                d0 += __shfl_xor(d0, off); d1 += __shfl_xor(d1, off);
                d2 += __shfl_xor(d2, off); d3 += __shfl_xor(d3, off);
            }
            float i0 = 1.f / (d0 + 1e-16f), i1 = 1.f / (d1 + 1e-16f);
            float i2 = 1.f / (d2 + 1e-16f), i3 = 1.f / (d3 + 1e-16f);
            wls[wid][lane] = make_float4(e0 * i0, e1 * i1, e2 * i2, e3 * i3); // 0 beyond deg

            int degm = max(deg, __shfl_xor(deg, 32));  // uniform loop bound, <= 32
            int base = sel * 32;
            float aA0 = 0.f, aB0 = 0.f, aA1 = 0.f, aB1 = 0.f;
            for (int j = 0; j < degm; j += 4) {
                int j0 = base + j, j1 = base + j + 1, j2 = base + j + 2, j3 = base + j + 3;
                int sa = __shfl(s, j0), sb = __shfl(s, j1);
                int sc_ = __shfl(s, j2), sd = __shfl(s, j3);
                float4 wa = wls[wid][j0], wb = wls[wid][j1];
                float4 wc = wls[wid][j2], wd = wls[wid][j3];
                uint2 ha = *(const uint2*)(hp + (size_t)sa * 64 + p0);
                uint2 hb = *(const uint2*)(hp + (size_t)sb * 64 + p0);
                uint2 hc = *(const uint2*)(hp + (size_t)sc_ * 64 + p0);
                uint2 hd = *(const uint2*)(hp + (size_t)sd * 64 + p0);
                float wAa = phsel ? wa.y : wa.x, wBa = phsel ? wa.w : wa.z;
                float wAb = phsel ? wb.y : wb.x, wBb = phsel ? wb.w : wb.z;
                float wAc = phsel ? wc.y : wc.x, wBc = phsel ? wc.w : wc.z;
                float wAd = phsel ? wd.y : wd.x, wBd = phsel ? wd.w : wd.z;
                aA0 += wAa * bl(ha.x); aB0 += wBa * bh(ha.x);
                aA1 += wAa * bl(ha.y); aB1 += wBa * bh(ha.y);
                aA0 += wAb * bl(hb.x); aB0 += wBb * bh(hb.x);
                aA1 += wAb * bl(hb.y); aB1 += wBb * bh(hb.y);
                aA0 += wAc * bl(hc.x); aB0 += wBc * bh(hc.x);
                aA1 += wAc * bl(hc.y); aB1 += wBc * bh(hc.y);
                aA0 += wAd * bl(hd.x); aB0 += wBd * bh(hd.x);
                aA1 += wAd * bl(hd.y); aB1 += wBd * bh(hd.y);
            }
            if (dv) {
                u32 w0 = (u32)f2bf(fmaxf(aA0 + biasA0, 0.f))
                       | ((u32)f2bf(fmaxf(aB0 + biasB0, 0.f)) << 16);
                u32 w1 = (u32)f2bf(fmaxf(aA1 + biasA1, 0.f))
                       | ((u32)f2bf(fmaxf(aB1 + biasB1, 0.f)) << 16);
                *(uint2*)(out + (size_t)d * 64 + p0) = make_uint2(w0, w1);
            }
        } else {
            // ---- fallback: process the pair sequentially with the full wave ----
            for (int q = 0; q < 2; q++) {
                int dq = db + q;
                if (dq >= n) break;
                int t0 = clampi(roff[dq], 0, E);
                int t1 = clampi(roff[dq + 1], t0, E);
                int dg = t1 - t0;
                float4 adv = *(const float4*)&adst[(size_t)dq * 4];
                if (dg <= 64) {
                    bool v = lane < dg;
                    int s = 0;
                    float e0 = 0.f, e1 = 0.f, e2 = 0.f, e3 = 0.f;
                    if (v) {
                        int2 ed = edata[t0 + lane];
                        s = ed.x;
                        float ea = __int_as_float(ed.y);
                        float4 av = *(const float4*)&asrc[(size_t)s * 4];
                        e0 = cexpf(lrelu(av.x + adv.x + ea * c0));
                        e1 = cexpf(lrelu(av.y + adv.y + ea * c1));
                        e2 = cexpf(lrelu(av.z + adv.z + ea * c2));
                        e3 = cexpf(lrelu(av.w + adv.w + ea * c3));
                    }
                    float d0 = e0, d1 = e1, d2 = e2, d3 = e3;
                    #pragma unroll
                    for (int off = 32; off > 0; off >>= 1) {
                        d0 += __shfl_xor(d0, off); d1 += __shfl_xor(d1, off);
                        d2 += __shfl_xor(d2, off); d3 += __shfl_xor(d3, off);
                    }
                    float i0 = 1.f / (d0 + 1e-16f), i1 = 1.f / (d1 + 1e-16f);
                    float i2 = 1.f / (d2 + 1e-16f), i3 = 1.f / (d3 + 1e-16f);
                    wls[wid][lane] = make_float4(e0 * i0, e1 * i1, e2 * i2, e3 * i3);

                    float aA0 = 0.f, aB0 = 0.f, aA1 = 0.f, aB1 = 0.f;
                    for (int j = 0; j < dg; j += 4) {
                        int j0 = j + sel, j1 = j + 2 + sel;
                        int sa = __shfl(s, j0), sb = __shfl(s, j1);
                        float4 wa = wls[wid][j0], wb = wls[wid][j1];
                        uint2 ha = *(const uint2*)(hp + (size_t)sa * 64 + p0);
                        uint2 hb = *(const uint2*)(hp + (size_t)sb * 64 + p0);
                        float wAa = phsel ? wa.y : wa.x, wBa = phsel ? wa.w : wa.z;
                        float wAb = phsel ? wb.y : wb.x, wBb = phsel ? wb.w : wb.z;
                        aA0 += wAa * bl(ha.x); aB0 += wBa * bh(ha.x);
                        aA1 += wAa * bl(ha.y); aB1 += wBa * bh(ha.y);
                        aA0 += wAb * bl(hb.x); aB0 += wBb * bh(hb.x);
                        aA1 += wAb * bl(hb.y); aB1 += wBb * bh(hb.y);
                    }
                    aA0 += __shfl_xor(aA0, 32); aB0 += __shfl_xor(aB0, 32);
                    aA1 += __shfl_xor(aA1, 32); aB1 += __shfl_xor(aB1, 32);
                    if (lane < 32) {
                        u32 w0 = (u32)f2bf(fmaxf(aA0 + biasA0, 0.f))
                               | ((u32)f2bf(fmaxf(aB0 + biasB0, 0.f)) << 16);
                        u32 w1 = (u32)f2bf(fmaxf(aA1 + biasA1, 0.f))
                               | ((u32)f2bf(fmaxf(aB1 + biasB1, 0.f)) << 16);
                        *(uint2*)(out + (size_t)dq * 64 + p0) = make_uint2(w0, w1);
                    }
                } else {
                    // general path: 2 passes (recompute exp in pass 2)
                    float d0 = 0.f, d1 = 0.f, d2 = 0.f, d3 = 0.f;
                    for (int idx = t0 + lane; idx < t1; idx += 64) {
                        int2 ed = edata[idx];
                        float ea = __int_as_float(ed.y);
                        float4 av = *(const float4*)&asrc[(size_t)ed.x * 4];
                        d0 += cexpf(lrelu(av.x + adv.x + ea * c0));
                        d1 += cexpf(lrelu(av.y + adv.y + ea * c1));
                        d2 += cexpf(lrelu(av.z + adv.z + ea * c2));
                        d3 += cexpf(lrelu(av.w + adv.w + ea * c3));
                    }
                    #pragma unroll
                    for (int off = 32; off > 0; off >>= 1) {
                        d0 += __shfl_xor(d0, off); d1 += __shfl_xor(d1, off);
                        d2 += __shfl_xor(d2, off); d3 += __shfl_xor(d3, off);
                    }
                    float i0 = 1.f / (d0 + 1e-16f), i1 = 1.f / (d1 + 1e-16f);
                    float i2 = 1.f / (d2 + 1e-16f), i3 = 1.f / (d3 + 1e-16f);
                    float iA = ghsel ? i1 : i0, iB = ghsel ? i3 : i2;
                    float cA = ghsel ? c1 : c0, cB = ghsel ? c3 : c2;
                    float aA = ghsel ? adv.y : adv.x, aB = ghsel ? adv.w : adv.z;
                    float accA = 0.f, accB = 0.f;
                    for (int idx = t0; idx < t1; idx++) {
                        int2 ed = edata[idx];
                        float ea = __int_as_float(ed.y);
                        float4 av = *(const float4*)&asrc[(size_t)ed.x * 4];
                        float wA = cexpf(lrelu((ghsel ? av.y : av.x) + aA + ea * cA)) * iA;
                        float wB = cexpf(lrelu((ghsel ? av.w : av.z) + aB + ea * cB)) * iB;
                        u32 hw = hp[(size_t)ed.x * 64 + lane];
                        accA += wA * bl(hw);
                        accB += wB * bh(hw);
                    }
                    float rA = fmaxf(accA + gbiasA, 0.f);
                    float rB = fmaxf(accB + gbiasB, 0.f);
                    out[(size_t)dq * 64 + lane] = (u32)f2bf(rA) | ((u32)f2bf(rB) << 16);
                }
            }
        }
    }
}

// ---------------- gat2, CACHED: 2 nodes/wave, 4-edge unrolled gather --------------------
__global__ __launch_bounds__(256) void k_gat2c(
    const u16* __restrict__ h, const float* __restrict__ asrc, const float* __restrict__ adst,
    const int2* __restrict__ edata, const int* __restrict__ roff,
    const int* __restrict__ flag, const float* __restrict__ consts, const void* bias,
    u16* __restrict__ out, int n, int E) {
    __shared__ float wls[4][64];
    int f = *flag;
    int gtid = blockIdx.x * 256 + threadIdx.x;
    int wv = gtid >> 6, lane = gtid & 63;
    int wid = (threadIdx.x >> 6);
    int nw = (gridDim.x * 256) >> 6;
    const float C = consts[4];
    const int hl = lane & 31;
    const int sel = lane >> 5;
    const int p0 = hl * 2;             // owned u16 pair (one u32)
    const float bias0 = load1(bias, p0, f);
    const float bias1 = load1(bias, p0 + 1, f);
    const float gbias = load1(bias, lane, f);

    for (int db = wv * 2; db < n; db += nw * 2) {
        int d = db + sel;
        bool dv = d < n;
        int s0 = dv ? clampi(roff[d], 0, E) : 0;
        int s1 = dv ? clampi(roff[d + 1], s0, E) : 0;
        int deg = s1 - s0;
        float ad = dv ? adst[d] : 0.f;

        if (__all(deg <= 32)) {
            bool v = hl < deg;
            int s = 0;
            float e = 0.f;
            if (v) {
                int2 ed = edata[s0 + hl];
                s = ed.x;
                e = cexpf(lrelu(asrc[s] + ad + __int_as_float(ed.y) * C));
            }
            float den = e;
            #pragma unroll
            for (int off = 16; off > 0; off >>= 1) den += __shfl_xor(den, off);
            float inv = 1.f / (den + 1e-16f);
            wls[wid][lane] = e * inv;                  // 0 beyond deg

            int degm = max(deg, __shfl_xor(deg, 32));
            int base = sel * 32;
            float a0 = 0.f, a1 = 0.f;
            for (int j = 0; j < degm; j += 4) {
                int j0 = base + j, j1 = base + j + 1, j2 = base + j + 2, j3 = base + j + 3;
                int sa = __shfl(s, j0), sb = __shfl(s, j1);
                int sc_ = __shfl(s, j2), sd = __shfl(s, j3);
                float wa = wls[wid][j0], wb = wls[wid][j1];
                float wc = wls[wid][j2], wd = wls[wid][j3];
                u32 ha = *(const u32*)(h + (size_t)sa * 64 + p0);
                u32 hb = *(const u32*)(h + (size_t)sb * 64 + p0);
                u32 hc = *(const u32*)(h + (size_t)sc_ * 64 + p0);
                u32 hd = *(const u32*)(h + (size_t)sd * 64 + p0);
                a0 += wa * bl(ha) + wb * bl(hb) + wc * bl(hc) + wd * bl(hd);
                a1 += wa * bh(ha) + wb * bh(hb) + wc * bh(hc) + wd * bh(hd);
            }
            if (dv) {
                u32 w = (u32)f2bf(a0 + bias0) | ((u32)f2bf(a1 + bias1) << 16);
                *(u32*)(out + (size_t)d * 64 + p0) = w;
            }
        } else {
            for (int q = 0; q < 2; q++) {
                int dq = db + q;
                if (dq >= n) break;
                int t0 = clampi(roff[dq], 0, E);
                int t1 = clampi(roff[dq + 1], t0, E);
                int dg = t1 - t0;
                float adq = adst[dq];
                if (dg <= 64) {
                    bool v = lane < dg;
                    int s = 0;
                    float e = 0.f;
                    if (v) {
                        int2 ed = edata[t0 + lane];
                        s = ed.x;
                        e = cexpf(lrelu(asrc[s] + adq + __int_as_float(ed.y) * C));
                    }
                    float den = e;
                    #pragma unroll
                    for (int off = 32; off > 0; off >>= 1) den += __shfl_xor(den, off);
                    float inv = 1.f / (den + 1e-16f);
                    wls[wid][lane] = e * inv;

                    float a0 = 0.f, a1 = 0.f;
                    for (int j = 0; j < dg; j += 4) {
                        int j0 = j + sel, j1 = j + 2 + sel;
                        int sa = __shfl(s, j0), sb = __shfl(s, j1);
                        float wa = wls[wid][j0], wb = wls[wid][j1];
                        u32 ha = *(const u32*)(h + (size_t)sa * 64 + p0);
                        u32 hb = *(const u32*)(h + (size_t)sb * 64 + p0);
                        a0 += wa * bl(ha) + wb * bl(hb);
                        a1 += wa * bh(ha) + wb * bh(hb);
                    }
                    a0 += __shfl_xor(a0, 32);
                    a1 += __shfl_xor(a1, 32);
                    if (lane < 32) {
                        u32 w = (u32)f2bf(a0 + bias0) | ((u32)f2bf(a1 + bias1) << 16);
                        *(u32*)(out + (size_t)dq * 64 + p0) = w;
                    }
                } else {
                    float den = 0.f;
                    for (int idx = t0 + lane; idx < t1; idx += 64) {
                        int2 ed = edata[idx];
                        den += cexpf(lrelu(asrc[ed.x] + adq + __int_as_float(ed.y) * C));
                    }
                    #pragma unroll
                    for (int off = 32; off > 0; off >>= 1) den += __shfl_xor(den, off);
                    float inv = 1.f / (den + 1e-16f);
                    float acc = 0.f;
                    for (int idx = t0; idx < t1; idx++) {
                        int2 ed = edata[idx];
                        float w = cexpf(lrelu(asrc[ed.x] + adq
                                              + __int_as_float(ed.y) * C)) * inv;
                        acc += w * bf2f(h[(size_t)ed.x * 64 + lane]);
                    }
                    out[(size_t)dq * 64 + lane] = f2bf(acc + gbias);
                }
            }
        }
    }
}

// ---------------- gat1/gat2 FALLBACK (recompute) ----------------------------------------
__global__ __launch_bounds__(256) void k_gat1f(
    const u32* __restrict__ hp, const float* __restrict__ asrc, const float* __restrict__ adst,
    const int2* __restrict__ edata, const int* __restrict__ roff,
    const int* __restrict__ flag, const float* __restrict__ consts, const void* bias,
    u32* __restrict__ out, int n, int E) {
    int f = *flag;
    int gtid = blockIdx.x * 256 + threadIdx.x;
    int wv = gtid >> 6, lane = gtid & 63;
    int nw = (gridDim.x * 256) >> 6;
    const float c0 = consts[0], c1 = consts[1], c2 = consts[2], c3 = consts[3];
    const int hsel = lane >> 5;
    const float biasA = load1(bias, lane, f);
    const float biasB = load1(bias, 64 + lane, f);

    for (int d = wv; d < n; d += nw) {
        int s0 = clampi(roff[d], 0, E);
        int s1 = clampi(roff[d + 1], s0, E);
        float4 adv = *(const float4*)&adst[d * 4];
        float d0 = 0.f, d1 = 0.f, d2 = 0.f, d3 = 0.f;
        for (int idx = s0 + lane; idx < s1; idx += 64) {
            int2 ed = edata[idx];
            float ea = __int_as_float(ed.y);
            float4 av = *(const float4*)&asrc[(size_t)ed.x * 4];
            d0 += cexpf(lrelu(av.x + adv.x + ea * c0));
            d1 += cexpf(lrelu(av.y + adv.y + ea * c1));
            d2 += cexpf(lrelu(av.z + adv.z + ea * c2));
            d3 += cexpf(lrelu(av.w + adv.w + ea * c3));
        }
        #pragma unroll
        for (int off = 32; off > 0; off >>= 1) {
            d0 += __shfl_xor(d0, off); d1 += __shfl_xor(d1, off);
            d2 += __shfl_xor(d2, off); d3 += __shfl_xor(d3, off);
        }
        float i0 = 1.f / (d0 + 1e-16f), i1 = 1.f / (d1 + 1e-16f);
        float i2 = 1.f / (d2 + 1e-16f), i3 = 1.f / (d3 + 1e-16f);
        float iA = hsel ? i1 : i0, iB = hsel ? i3 : i2;
        float cA = hsel ? c1 : c0, cB = hsel ? c3 : c2;
        float aA = hsel ? adv.y : adv.x, aB = hsel ? adv.w : adv.z;

        float accA = 0.f, accB = 0.f;
        for (int idx = s0; idx < s1; idx++) {
            int2 ed = edata[idx];
            float ea = __int_as_float(ed.y);
            float4 av = *(const float4*)&asrc[(size_t)ed.x * 4];
            float wA = cexpf(lrelu((hsel ? av.y : av.x) + aA + ea * cA)) * iA;
            float wB = cexpf(lrelu((hsel ? av.w : av.z) + aB + ea * cB)) * iB;
            u32 hw = hp[(size_t)ed.x * 64 + lane];
            accA += wA * bl(hw);
            accB += wB * bh(hw);
        }
        float rA = fmaxf(accA + biasA, 0.f);
        float rB = fmaxf(accB + biasB, 0.f);
        out[(size_t)d * 64 + lane] = (u32)f2bf(rA) | ((u32)f2bf(rB) << 16);
    }
}

__global__ __launch_bounds__(256) void k_gat2f(
    const u16* __restrict__ h, const float* __restrict__ asrc, const float* __restrict__ adst,
    const int2* __restrict__ edata, const int* __restrict__ roff,
    const int* __restrict__ flag, const float* __restrict__ consts, const void* bias,
    u16* __restrict__ out, int n, int E) {
    int f = *flag;
    int gtid = blockIdx.x * 256 + threadIdx.x;
    int wv = gtid >> 6, lane = gtid & 63;
    int nw = (gridDim.x * 256) >> 6;
    const float C = consts[4];
    const float biasL = load1(bias, lane, f);

    for (int d = wv; d < n; d += nw) {
        int s0 = clampi(roff[d], 0, E);
        int s1 = clampi(roff[d + 1], s0, E);
        float ad = adst[d];
        float den = 0.f;
        for (int idx = s0 + lane; idx < s1; idx += 64) {
            int2 ed = edata[idx];
            den += cexpf(lrelu(asrc[ed.x] + ad + __int_as_float(ed.y) * C));
        }
        #pragma unroll
        for (int off = 32; off > 0; off >>= 1) den += __shfl_xor(den, off);
        float inv = 1.f / (den + 1e-16f);

        float acc = 0.f;
        for (int idx = s0; idx < s1; idx++) {
            int2 ed = edata[idx];
            float w = cexpf(lrelu(asrc[ed.x] + ad + __int_as_float(ed.y) * C)) * inv;
            acc += w * bf2f(h[(size_t)ed.x * 64 + lane]);
        }
        out[(size_t)d * 64 + lane] = f2bf(acc + biasL);
    }
}

// ---------------- pooling ---------------------------------------------------------------
__global__ __launch_bounds__(256) void k_pool2(
    const u16* __restrict__ agg2, const int* __restrict__ batch,
    float* __restrict__ pool, float* __restrict__ cnt, int n, int G, int rpb) {
    __shared__ float lp[POOL_MAXG * 64];
    __shared__ float lc[POOL_MAXG];
    int t = threadIdx.x;
    for (int i = t; i < G * 64; i += 256) lp[i] = 0.f;
    for (int i = t; i < G; i += 256) lc[i] = 0.f;
    __syncthreads();
    int lane = t & 63;
    int rl = t >> 6;                      // row-lane 0..3
    int r0 = blockIdx.x * rpb;
    int r1 = min(r0 + rpb, n);
    float acc = 0.f, cacc = 0.f;
    int curg = -1;
    for (int j = r0 + rl; j < r1; j += 4) {
        int g = clampi(batch[j], 0, G - 1);
        float v = bf2f(agg2[(size_t)j * 64 + lane]);
        if (g != curg) {                  // rare: batch is sorted
            if (curg >= 0) {
                atomicAdd(&lp[curg * 64 + lane], acc);
                if (lane == 0) atomicAdd(&lc[curg], cacc);
            }
            acc = 0.f; cacc = 0.f; curg = g;
        }
        acc += v; cacc += 1.f;
    }
    if (curg >= 0) {
        atomicAdd(&lp[curg * 64 + lane], acc);
        if (lane == 0) atomicAdd(&lc[curg], cacc);
    }
    __syncthreads();
    for (int i = t; i < G * 64; i += 256) {
        float v = lp[i];
        if (v != 0.f) atomicAdd(&pool[i], v);
    }
    for (int i = t; i < G; i += 256) {
        float v = lc[i];
        if (v != 0.f) atomicAdd(&cnt[i], v);
    }
}

// fallback for G > POOL_MAXG
__global__ void k_pool(const u16* __restrict__ agg2, const int* __restrict__ batch,
                       float* __restrict__ pool, float* __restrict__ cnt, int n, int G) {
    int t = blockIdx.x * 256 + threadIdx.x;
    int nb8 = (n + 7) / 8;
    if (t >= nb8 * 64) return;
    int base = (t >> 6) * 8;
    int c = t & 63;
    int end = min(base + 8, n);
    float acc = 0.f, cacc = 0.f;
    int curg = clampi(batch[base], 0, G - 1);
    for (int j = base; j < end; j++) {
        int g = clampi(batch[j], 0, G - 1);
        if (g != curg) {
            atomicAdd(&pool[curg * 64 + c], acc);
            if (c == 0) atomicAdd(&cnt[curg], cacc);
            acc = 0.f; cacc = 0.f; curg = g;
        }
        acc += bf2f(agg2[(size_t)j * 64 + c]);
        cacc += 1.f;
    }
    atomicAdd(&pool[curg * 64 + c], acc);
    if (c == 0) atomicAdd(&cnt[curg], cacc);
}

__global__ void k_head(const float* __restrict__ pool, const float* __restrict__ cnt,
                       const void* Wp, const void* bp, const int* __restrict__ flag,
                       void* out, int G) {
    int f = *flag;
    int g = threadIdx.x;
    if (g >= G) return;
    float s = 0.f;
    for (int c = 0; c < 64; c++) s += pool[g * 64 + c] * load1(Wp, c, f);
    float cv = cnt[g];
    if (!(cv > 0.f)) cv = 1.f;
    float r = s / cv + load1(bp, 0, f);
    if (f) ((float*)out)[g] = r;
    else   ((u16*)out)[g] = f2bf(r);
}

// ---------------- launch ----------------------------------------------------------------
extern "C" void kernel_launch(void* const* d_in, const int* in_sizes, int n_in,
                              void* d_out, int out_size, void* d_ws, size_t ws_size,
                              hipStream_t stream) {
    const void* x    = d_in[0];
    const int* ei    = (const int*)d_in[1];
    const void* eattr = d_in[2];
    const int* batch = (const int*)d_in[3];
    const void* W1   = d_in[4];
    const void* as1  = d_in[5];
    const void* ad1  = d_in[6];
    const void* We1  = d_in[7];
    const void* ae1  = d_in[8];
    const void* b1   = d_in[9];
    const void* W2   = d_in[10];
    const void* as2  = d_in[11];
    const void* ad2  = d_in[12];
    const void* We2  = d_in[13];
    const void* ae2  = d_in[14];
    const void* b2   = d_in[15];
    const void* Wp   = d_in[16];
    const void* bp   = d_in[17];

    const int N = in_sizes[3];
    const int E = in_sizes[2];
    const int G = out_size;
    const int* src = ei;
    const int* dst = ei + E;
    const int B = (N + 255) >> 8;

    char* p = (char*)d_ws;
    auto alloc = [&](size_t bytes) -> char* {
        char* r = p;
        p += (bytes + 255) & ~(size_t)255;
        return r;
    };
    int* flag    = (int*)alloc(32);
    float* consts = (float*)alloc(2048);
    int* roff    = (int*)alloc((size_t)(N + 1) * 4);
    int* rpos    = (int*)alloc((size_t)N * 4);
    int* bsum    = (int*)alloc(256 * 4);
    int* bcnt    = (int*)alloc((size_t)(MAXB * 3 + 1) * 4);
    int* bbase   = bcnt + MAXB;          // B+1 entries
    int* bfront  = bbase + MAXB + 1;     // B entries
    int2* edata  = (int2*)alloc((size_t)E * 8);
    float* pool  = (float*)alloc((size_t)(G * 64 + G) * 4);
    float* cnt   = pool + (size_t)G * 64;
    float* asrc1 = (float*)alloc((size_t)N * 4 * 4);
    float* adst1 = (float*)alloc((size_t)N * 4 * 4);
    float* asrc2 = asrc1;             // alias: dead after gat1
    float* adst2 = adst1;
    u16* agg1    = (u16*)alloc((size_t)N * 128 * 2);
    u16* h1      = (u16*)alloc((size_t)N * 128 * 2);
    u16* h2      = h1;                // alias: h1 dead after gat1
    u16* agg2    = h1 + (size_t)N * 64;
    int2* stagedA = (int2*)alloc((size_t)E * 8);   // {src24|d8<<24, ea}
    size_t full_need = (size_t)(p - (char*)d_ws);
    const bool cached = (ws_size >= full_need);
    const bool binned = cached && (B <= MAXB) && (N <= (1 << 24));

    // GG = ceil(N/128): gemm handles tiles (bid, bid+GG); nBin = ceil(E/2048) binA blocks
    const int GG = (N + 127) >> 7;
    const int nBin = (E + 2047) / 2048;

    k_init<<<1, 256, 0, stream>>>((const u32*)x, flag, bcnt, B,
                                  We1, ae1, We2, ae2, as1, ad1, as2, ad2,
                                  consts, pool, G * 64 + G);

    if (binned) {
        // CSR prefix (edge-only deps) first, then FUSED gemm128 || binA overlap.
        k_bhist2<<<512, 256, 0, stream>>>(dst, bcnt, E, N, B);
        k_bscan<<<1, 256, 0, stream>>>(bcnt, bbase, bfront, roff, B, N, E);
        k_fuse_gemm_binA<<<GG + nBin, 256, 0, stream>>>(
            x, W1, flag, h1, consts, asrc1, adst1, N, GG,
            dst, src, eattr, bfront, stagedA, E, N, B);
        k_binB2<<<B, 256, 0, stream>>>(stagedA, bbase, roff, edata, N, E, B);
    } else {
        k_gemm_mfma<128><<<GG, 256, 0, stream>>>(x, W1, flag, -1, h1, consts,
                                                 asrc1, adst1, N);
        int NB = (N + 255) / 256;
        k_zero<<<(N + 255) / 256, 256, 0, stream>>>(rpos, N);
        k_bhist<<<512, 256, 0, stream>>>(dst, rpos, bcnt, E, N, B);
        k_scan1<<<NB, 256, 0, stream>>>(rpos, roff + 1, bsum, N);
        k_scan3b<<<(N + 256) / 256, 256, 0, stream>>>(roff, bsum, rpos, N, NB);
        k_scatter<<<(E + 255) / 256, 256, 0, stream>>>(dst, src, eattr, flag, rpos,
                                                       edata, E, N);
    }

    // right-sized gat grids: each block = 4 waves x 2 nodes = 8 nodes
    int gatBlocks = (N + 7) / 8;
    if (cached) {
        k_gat1c<<<gatBlocks, 256, 0, stream>>>((const u32*)h1, asrc1, adst1, edata, roff,
                                               flag, consts, b1, (u32*)agg1, N, E);
    } else {
        k_gat1f<<<gatBlocks, 256, 0, stream>>>((const u32*)h1, asrc1, adst1, edata, roff,
                                               flag, consts, b1, (u32*)agg1, N, E);
    }
    // gemm + fused coef2
    k_gemm_mfma<64><<<GG, 256, 0, stream>>>(agg1, W2, flag, 0, h2, consts,
                                            asrc2, adst2, N);
    if (cached) {
        k_gat2c<<<gatBlocks, 256, 0, stream>>>(h2, asrc2, adst2, edata, roff, flag,
                                               consts, b2, agg2, N, E);
    } else {
        k_gat2f<<<gatBlocks, 256, 0, stream>>>(h2, asrc2, adst2, edata, roff, flag,
                                               consts, b2, agg2, N, E);
    }
    if (G <= POOL_MAXG) {
        int rpb = (N + 1023) / 1024;
        if (rpb < 8) rpb = 8;
        int pblocks = (N + rpb - 1) / rpb;
        k_pool2<<<pblocks, 256, 0, stream>>>(agg2, batch, pool, cnt, N, G, rpb);
    } else {
        k_pool<<<(((N + 7) / 8) * 64 + 255) / 256, 256, 0, stream>>>(agg2, batch, pool,
                                                                     cnt, N, G);
    }
    k_head<<<1, 64, 0, stream>>>(pool, cnt, Wp, bp, flag, d_out, G);
}